// Round 11
// baseline (268.741 us; speedup 1.0000x reference)
//
#include <hip/hip_runtime.h>
#include <stdint.h>

#define NN 2048
#define MM 2048
#define NSAMP 131072   // B*N*K

typedef float  fv4 __attribute__((ext_vector_type(4)));
typedef short  bfv8 __attribute__((ext_vector_type(8)));
typedef short  bfv4 __attribute__((ext_vector_type(4)));
typedef unsigned short u16;
typedef unsigned long long u64;

__device__ inline u16 f2bf(float x){
  unsigned u = __float_as_uint(x);
  return (u16)((u + 0x7FFFu + ((u>>16)&1u)) >> 16);
}
__device__ inline float bf2f(u16 u){ return __uint_as_float(((unsigned)u)<<16); }
#define MFMA16 __builtin_amdgcn_mfma_f32_16x16x32_bf16

// ---------------------------------------------------------------------------
// k_front: weights pack | qkv MFMA (fused transpose) | KNN + pos moments
// ---------------------------------------------------------------------------
__global__ __launch_bounds__(256) void k_front(
    const float* __restrict__ pq, const float* __restrict__ ps,
    const float* __restrict__ fq, const float* __restrict__ fs,
    const float* __restrict__ Wq, const float* __restrict__ Wk, const float* __restrict__ Wv,
    const float* __restrict__ Wp2, const float* __restrict__ Wa2, const float* __restrict__ We,
    const float* __restrict__ bq, const float* __restrict__ bk, const float* __restrict__ bv,
    u16* __restrict__ Wp2bf, u16* __restrict__ Wa2bf, u16* __restrict__ Webf,
    float* __restrict__ qT, float* __restrict__ kT, float* __restrict__ vT,
    int* __restrict__ idxb, float* __restrict__ posPart) {
  __shared__ __align__(16) unsigned char smem[35072];
  const int bid = blockIdx.x;
  const int t = threadIdx.x;

  if (bid < 64) {
    int gid = bid * 256 + t;   // 16384
    if (gid < 4096)  Wp2bf[gid] = f2bf(Wp2[gid]);
    if (gid < 16384) Wa2bf[gid] = f2bf(Wa2[gid]);
    if (gid < 8192)  Webf[gid]  = f2bf(We[gid]);
    return;
  }

  if (bid < 320) {
    u16* tile0 = (u16*)smem;              // [32][136]
    u16* tile1 = (u16*)(smem + 8704);
    int r = bid - 64;
    int b = r >> 6, p0 = (r & 63) * 32;
    int w = t >> 6, l = t & 63, lq = l >> 4, ln = l & 15;
    {
      int cq = t >> 3, n4 = (t & 7) * 4;
      #pragma unroll
      for (int it = 0; it < 4; ++it) {
        int c = it * 32 + cq;
        fv4 vq = *(const fv4*)&fq[(b*128 + c)*2048 + p0 + n4];
        fv4 vs = *(const fv4*)&fs[(b*128 + c)*2048 + p0 + n4];
        #pragma unroll
        for (int j = 0; j < 4; ++j) {
          tile0[(n4 + j)*136 + c] = f2bf(vq[j]);
          tile1[(n4 + j)*136 + c] = f2bf(vs[j]);
        }
      }
    }
    bfv8 A[3][4];
    #pragma unroll
    for (int mat = 0; mat < 3; ++mat) {
      const float* Wf = mat == 0 ? Wq : (mat == 1 ? Wk : Wv);
      #pragma unroll
      for (int kk = 0; kk < 4; ++kk) {
        const float* src = Wf + (w*16 + ln)*128 + kk*32 + lq*8;
        fv4 a0 = *(const fv4*)src, a1 = *(const fv4*)(src + 4);
        u16 tmp[8];
        #pragma unroll
        for (int e = 0; e < 4; ++e) { tmp[e] = f2bf(a0[e]); tmp[4+e] = f2bf(a1[e]); }
        A[mat][kk] = *(const bfv8*)tmp;
      }
    }
    __syncthreads();
    fv4 acc[3][2];
    #pragma unroll
    for (int mat = 0; mat < 3; ++mat) {
      const u16* tl = mat == 0 ? tile0 : tile1;
      #pragma unroll
      for (int nt = 0; nt < 2; ++nt) {
        fv4 a = {0.f,0.f,0.f,0.f};
        #pragma unroll
        for (int kk = 0; kk < 4; ++kk) {
          bfv8 bb = *(const bfv8*)&tl[(nt*16 + ln)*136 + kk*32 + lq*8];
          a = MFMA16(A[mat][kk], bb, a, 0, 0, 0);
        }
        acc[mat][nt] = a;
      }
    }
    #pragma unroll
    for (int mat = 0; mat < 3; ++mat) {
      float* dst = mat == 0 ? qT : (mat == 1 ? kT : vT);
      const float* bia = mat == 0 ? bq : (mat == 1 ? bk : bv);
      fv4 bq4 = *(const fv4*)&bia[w*16 + lq*4];
      #pragma unroll
      for (int nt = 0; nt < 2; ++nt) {
        fv4 o = acc[mat][nt] + bq4;
        *(fv4*)&dst[(b*NN + p0 + nt*16 + ln)*64 + w*16 + lq*4] = o;
      }
    }
    return;
  }

  // ---- KNN ----
  {
    u64*   cand = (u64*)smem;
    float* sacc = (float*)(smem + 34816);
    int w = t >> 6, lane = t & 63;
    int blk = bid - 320;
    int qi = blk * 4 + w;
    int b = qi >> 11, n = qi & 2047;
    const float* pqb = pq + b * 3 * NN;
    const float* psb = ps + b * 3 * MM;
    float qx = pqb[n], qy = pqb[NN + n], qz = pqb[2 * NN + n];
    float qq = qx * qx + qy * qy + qz * qz;

    u64 A[16], Bv[16];
    #pragma unroll
    for (int j = 0; j < 16; ++j) {
      int m = lane + 64 * j;
      float sx = psb[m], sy = psb[MM + m], sz = psb[2 * MM + m];
      float ss  = sx * sx + sy * sy + sz * sz;
      float d2 = qq + ss - 2.f * (qx * sx + qy * sy + qz * sz);
      unsigned bu = __float_as_uint(d2);
      bu = (bu & 0x80000000u) ? ~bu : (bu | 0x80000000u);
      A[j] = (((u64)bu) << 32) | (unsigned)m;
    }
    #pragma unroll
    for (int j = 0; j < 16; ++j) {
      int m = lane + 64 * (j + 16);
      float sx = psb[m], sy = psb[MM + m], sz = psb[2 * MM + m];
      float ss  = sx * sx + sy * sy + sz * sz;
      float d2 = qq + ss - 2.f * (qx * sx + qy * sy + qz * sz);
      unsigned bu = __float_as_uint(d2);
      bu = (bu & 0x80000000u) ? ~bu : (bu | 0x80000000u);
      Bv[j] = (((u64)bu) << 32) | (unsigned)m;
    }
    #pragma unroll
    for (int k = 2; k <= 16; k <<= 1) {
      #pragma unroll
      for (int j = k >> 1; j > 0; j >>= 1) {
        #pragma unroll
        for (int i = 0; i < 16; ++i) {
          int l2 = i ^ j;
          if (l2 > i) {
            bool up = ((i & k) == 0);
            { u64 x = A[i], y = A[l2];
              bool sw = up ? (y < x) : (x < y);
              A[i] = sw ? y : x;  A[l2] = sw ? x : y; }
            { u64 x = Bv[i], y = Bv[l2];
              bool sw = up ? (y < x) : (x < y);
              Bv[i] = sw ? y : x; Bv[l2] = sw ? x : y; }
          }
        }
      }
    }
    #pragma unroll
    for (int i = 0; i < 16; ++i) {
      u64 y = Bv[15 - i];
      A[i] = A[i] < y ? A[i] : y;
    }
    #pragma unroll
    for (int j = 8; j > 0; j >>= 1) {
      #pragma unroll
      for (int i = 0; i < 16; ++i) {
        int l2 = i ^ j;
        if (l2 > i) {
          u64 x = A[i], y = A[l2];
          bool sw = (y < x);
          A[i] = sw ? y : x;  A[l2] = sw ? x : y;
        }
      }
    }
    #pragma unroll
    for (int i = 0; i < 16; ++i) cand[w*1088 + lane*17 + i] = A[i];
    float s0=0.f,s1=0.f,s2=0.f,s3=0.f,s4=0.f,s5=0.f,s6=0.f,s7=0.f,s8=0.f;
    int head = 0;
    for (int r = 0; r < 16; ++r) {
      u64 v = (head < 16) ? cand[w*1088 + lane*17 + head] : ~0ULL;
      u64 mv = v;
      #pragma unroll
      for (int off = 32; off > 0; off >>= 1) {
        u64 o = __shfl_xor(mv, off, 64);
        mv = o < mv ? o : mv;
      }
      if (v == mv) head++;
      unsigned m = (unsigned)(mv & 0xFFFFFFFFu);
      if (lane == 0) idxb[qi * 16 + r] = (int)m;
      float r0 = qx - psb[m], r1 = qy - psb[MM + m], r2 = qz - psb[2*MM + m];
      s0 += r0; s1 += r1; s2 += r2;
      s3 += r0*r0; s4 += r0*r1; s5 += r0*r2;
      s6 += r1*r1; s7 += r1*r2; s8 += r2*r2;
    }
    if (lane == 0) {
      sacc[w*9+0]=s0; sacc[w*9+1]=s1; sacc[w*9+2]=s2; sacc[w*9+3]=s3; sacc[w*9+4]=s4;
      sacc[w*9+5]=s5; sacc[w*9+6]=s6; sacc[w*9+7]=s7; sacc[w*9+8]=s8;
    }
    __syncthreads();
    if (t < 9) posPart[blk * 12 + t] =
        sacc[t] + sacc[9 + t] + sacc[18 + t] + sacc[27 + t];
  }
}

// ---------------------------------------------------------------------------
// y-stats (grid 1024, 8 pts/block): absorbs pos-BN fold (per-block redundant);
// Gram partials in bf16; block 0 publishes Wp1f/bp1f for k_main.
// ---------------------------------------------------------------------------
__global__ __launch_bounds__(256) void k_ystats(
    const float* __restrict__ pq, const float* __restrict__ ps,
    const float* __restrict__ qT, const float* __restrict__ kT,
    const int* __restrict__ idxb,
    const float* __restrict__ Wp1, const float* __restrict__ bp1,
    const float* __restrict__ gp, const float* __restrict__ btp,
    const float* __restrict__ posPart,
    const u16* __restrict__ Wp2bf, const float* __restrict__ bp2,
    u16* __restrict__ Gpart16, float* __restrict__ ySumPart,
    float* __restrict__ Wp1fG, float* __restrict__ bp1fG) {
  __shared__ __align__(16) unsigned char smem[22144];
  u16*   hp   = (u16*)smem;                 // [64 s][72 i] bf16
  u16*   y2   = (u16*)(smem + 9216);        // [64 d][72 s] bf16
  float* r3   = (float*)(smem + 18432);     // 192
  float* qc   = (float*)(smem + 19200);     // 256
  int*   idxA = (int*)(smem + 20224);       // 64
  float* sWp1 = (float*)(smem + 20480);     // 192
  float* sbp1 = (float*)(smem + 21248);     // 64
  float* sbp2 = (float*)(smem + 21504);     // 64
  float* redp = (float*)(smem + 21760);     // 4*9 + 9

  const int t = threadIdx.x;
  const int w = t >> 6, l = t & 63, lq = l >> 4, ln = l & 15;
  const int d0 = 16*w + lq*4;

  // ---- integrated pos-BN fold (each block computes its own Wp1f) ----
  {
    float s[9];
    #pragma unroll
    for (int i = 0; i < 9; ++i) s[i] = 0.f;
    #pragma unroll
    for (int it = 0; it < 8; ++it) {
      const float* p = posPart + (it * 256 + t) * 12;
      fv4 a = *(const fv4*)p;
      fv4 b4 = *(const fv4*)(p + 4);
      float c8 = p[8];
      s[0]+=a.x; s[1]+=a.y; s[2]+=a.z; s[3]+=a.w;
      s[4]+=b4.x; s[5]+=b4.y; s[6]+=b4.z; s[7]+=b4.w;
      s[8]+=c8;
    }
    #pragma unroll
    for (int off = 32; off > 0; off >>= 1)
      #pragma unroll
      for (int i = 0; i < 9; ++i) s[i] += __shfl_xor(s[i], off, 64);
    if (l == 0)
      #pragma unroll
      for (int i = 0; i < 9; ++i) redp[w*9 + i] = s[i];
    __syncthreads();
    if (t < 9) redp[36 + t] = redp[t] + redp[9+t] + redp[18+t] + redp[27+t];
    __syncthreads();
    if (t < 64) {
      const float* st = redp + 36;
      int d = t;
      const float invN = 1.f / (float)NSAMP;
      float m0 = st[0]*invN, m1 = st[1]*invN, m2 = st[2]*invN;
      float C00 = st[3]*invN - m0*m0, C01 = st[4]*invN - m0*m1, C02 = st[5]*invN - m0*m2;
      float C11 = st[6]*invN - m1*m1, C12 = st[7]*invN - m1*m2, C22 = st[8]*invN - m2*m2;
      float w0 = Wp1[d*3], w1 = Wp1[d*3+1], w2 = Wp1[d*3+2];
      float mean = w0*m0 + w1*m1 + w2*m2 + bp1[d];
      float var = w0*w0*C00 + w1*w1*C11 + w2*w2*C22 + 2.f*(w0*w1*C01 + w0*w2*C02 + w1*w2*C12);
      float scale = gp[d] * rsqrtf(var + 1e-5f);
      sWp1[d*3]   = scale * w0;
      sWp1[d*3+1] = scale * w1;
      sWp1[d*3+2] = scale * w2;
      float bf = btp[d] + scale * (bp1[d] - mean);
      sbp1[d] = bf;
      sbp2[d] = bp2[d];
      if (blockIdx.x == 0) {
        Wp1fG[d*3] = sWp1[d*3]; Wp1fG[d*3+1] = sWp1[d*3+1]; Wp1fG[d*3+2] = sWp1[d*3+2];
        bp1fG[d] = bf;
      }
    }
  }
  bfv8 Ape[2];
  #pragma unroll
  for (int kk = 0; kk < 2; ++kk)
    Ape[kk] = *(const bfv8*)(Wp2bf + (16*w + ln)*64 + kk*32 + lq*8);

  fv4 gacc[4];
  #pragma unroll
  for (int nt = 0; nt < 4; ++nt) gacc[nt] = (fv4){0.f,0.f,0.f,0.f};
  float ys[4] = {0.f, 0.f, 0.f, 0.f};
  __syncthreads();

  for (int ch = 0; ch < 2; ++ch) {
    const int p0 = blockIdx.x * 8 + ch * 4;
    const int b  = p0 >> 11;
    const int bN = b * 2048;
    if (t < 64) idxA[t] = idxb[p0*16 + t];
    qc[t] = qT[(p0 + (t>>6))*64 + (t & 63)];
    __syncthreads();
    if (t < 192) { int c = t >> 6, s = t & 63; int n = (p0 + (s>>4)) & 2047;
      r3[c*64 + s] = pq[(b*3+c)*NN + n] - ps[(b*3+c)*MM + idxA[s]]; }
    __syncthreads();
    { int s = t >> 2, iq = t & 3;
      float r0 = r3[s], r1 = r3[64+s], r2 = r3[128+s];
      u16 tmp[16];
      #pragma unroll
      for (int e = 0; e < 16; ++e) { int i = iq*16 + e;
        float v = sbp1[i] + sWp1[i*3]*r0 + sWp1[i*3+1]*r1 + sWp1[i*3+2]*r2;
        tmp[e] = f2bf(fmaxf(v, 0.f)); }
      *(bfv8*)&hp[s*72 + iq*16]     = *(const bfv8*)&tmp[0];
      *(bfv8*)&hp[s*72 + iq*16 + 8] = *(const bfv8*)&tmp[8];
    }
    __syncthreads();
    {
      fv4 pe[4];
      #pragma unroll
      for (int nt = 0; nt < 4; ++nt) {
        fv4 acc = {0.f,0.f,0.f,0.f};
        #pragma unroll
        for (int kk = 0; kk < 2; ++kk) {
          bfv8 bb = *(const bfv8*)&hp[(nt*16 + ln)*72 + kk*32 + lq*8];
          acc = MFMA16(Ape[kk], bb, acc, 0, 0, 0);
        }
        pe[nt] = acc;
      }
      fv4 bp2q = *(const fv4*)&sbp2[d0];
      #pragma unroll
      for (int nt = 0; nt < 4; ++nt) {
        int s = nt*16 + ln;
        int mi = idxA[s];
        fv4 kg = *(const fv4*)(kT + (bN + mi)*64 + d0);
        fv4 qv = *(const fv4*)&qc[nt*64 + d0];
        fv4 yv = qv - kg + pe[nt] + bp2q;
        #pragma unroll
        for (int r = 0; r < 4; ++r) { y2[(d0 + r)*72 + s] = f2bf(yv[r]); ys[r] += yv[r]; }
      }
    }
    __syncthreads();
    #pragma unroll
    for (int kk = 0; kk < 2; ++kk) {
      bfv8 aa = *(const bfv8*)&y2[(16*w + ln)*72 + kk*32 + lq*8];
      #pragma unroll
      for (int nt = 0; nt < 4; ++nt) {
        bfv8 bb = *(const bfv8*)&y2[(nt*16 + ln)*72 + kk*32 + lq*8];
        gacc[nt] = MFMA16(aa, bb, gacc[nt], 0, 0, 0);
      }
    }
    __syncthreads();
  }
  #pragma unroll
  for (int nt = 0; nt < 4; ++nt)
    #pragma unroll
    for (int r = 0; r < 4; ++r)
      Gpart16[blockIdx.x*4096 + (16*w + lq*4 + r)*64 + nt*16 + ln] = f2bf(gacc[nt][r]);
  #pragma unroll
  for (int off = 1; off <= 8; off <<= 1) {
    #pragma unroll
    for (int r = 0; r < 4; ++r) ys[r] += __shfl_xor(ys[r], off, 64);
  }
  if (ln == 0) {
    #pragma unroll
    for (int r = 0; r < 4; ++r) ySumPart[blockIdx.x*64 + d0 + r] = ys[r];
  }
}

// ---------------------------------------------------------------------------
// reduce Gram (bf16, 1024 partials) / ySum. grid 257.
// ---------------------------------------------------------------------------
__global__ __launch_bounds__(256) void k_gred(
    const u16* __restrict__ Gpart16, const float* __restrict__ ySumPart,
    float* __restrict__ G, float* __restrict__ ySum) {
  __shared__ float red[256];
  int bid = blockIdx.x, t = threadIdx.x;
  if (bid < 256) {
    int j0 = bid * 16, tj = t & 15, st = t >> 4;   // 16 stripes x 64 p
    float s = 0.f;
    for (int p = 0; p < 64; ++p)
      s += bf2f(Gpart16[(st*64 + p)*4096 + j0 + tj]);
    red[t] = s;
    __syncthreads();
    if (t < 16) {
      float ss = 0.f;
      #pragma unroll
      for (int k = 0; k < 16; ++k) ss += red[k*16 + t];
      G[j0 + t] = ss;
    }
  } else {
    if (t < 64) {
      float s = 0.f;
      for (int p = 0; p < 1024; ++p) s += ySumPart[p*64 + t];
      ySum[t] = s;
    }
  }
}

// ---------------------------------------------------------------------------
// fold attn-BN into Wa1/ba1; emit bf16 Wa1f
// ---------------------------------------------------------------------------
__global__ __launch_bounds__(256) void k_attnfinal(
    const float* __restrict__ Wa1, const float* __restrict__ ba1,
    const float* __restrict__ ga, const float* __restrict__ bta,
    const float* __restrict__ ySum, const float* __restrict__ G,
    u16* __restrict__ Wa1fbf, float* __restrict__ ba1f) {
  __shared__ float red[256];
  __shared__ float mu[64];
  __shared__ float sc[1];
  int h = blockIdx.x, t = threadIdx.x;
  const float invN = 1.f / (float)NSAMP;
  if (t < 64) mu[t] = ySum[t] * invN;
  __syncthreads();
  float acc = 0.f;
  #pragma unroll
  for (int e = 0; e < 16; ++e) {
    int pi = t*16 + e, i = pi >> 6, j = pi & 63;
    float cov = G[pi]*invN - mu[i]*mu[j];
    acc += Wa1[h*64 + i] * Wa1[h*64 + j] * cov;
  }
  red[t] = acc;
  __syncthreads();
  for (int s = 128; s > 0; s >>= 1) { if (t < s) red[t] += red[t + s]; __syncthreads(); }
  float var = red[0];
  __syncthreads();
  red[t] = (t < 64) ? Wa1[h*64 + t] * mu[t] : 0.f;
  __syncthreads();
  for (int s = 128; s > 0; s >>= 1) { if (t < s) red[t] += red[t + s]; __syncthreads(); }
  if (t == 0) {
    float mean  = red[0] + ba1[h];
    float scale = ga[h] * rsqrtf(var + 1e-5f);
    sc[0] = scale;
    ba1f[h] = bta[h] + scale * (ba1[h] - mean);
  }
  __syncthreads();
  if (t < 64) Wa1fbf[h*64 + t] = f2bf(sc[0] * Wa1[h*64 + t]);
}

// ---------------------------------------------------------------------------
// main fused kernel: grid 1024, 8 pts/block (2 chunks of 4), shuffle-softmax
// (no at/vt LDS, val in registers), agg in LDS, fused epilogue.
// ---------------------------------------------------------------------------
__global__ __launch_bounds__(256, 3) void k_main(
    const float* __restrict__ pq, const float* __restrict__ ps,
    const float* __restrict__ qT, const float* __restrict__ kT, const float* __restrict__ vT,
    const int* __restrict__ idxb,
    const float* __restrict__ Wp1f, const float* __restrict__ bp1f,
    const u16* __restrict__ Wp2bf, const float* __restrict__ bp2,
    const u16* __restrict__ Wa1fbf, const float* __restrict__ ba1f,
    const u16* __restrict__ Wa2bf, const float* __restrict__ ba2,
    const u16* __restrict__ Webf, const float* __restrict__ be,
    const float* __restrict__ fq, float* __restrict__ out) {
  __shared__ __align__(16) unsigned char smem[48896];
  u16*   hp   = (u16*)smem;                    // [64 s][72 i] (aliases ha)
  u16*   ha   = (u16*)smem;                    // [64 s][264 h]
  u16*   ylds = (u16*)(smem + 33792);          // [64 s][72 d]
  u16*   agg  = (u16*)(smem + 43008);          // [8 p][72 d] bf16
  float* r3   = (float*)(smem + 44288);        // 192
  float* qc   = (float*)(smem + 45056);        // 256
  int*   idxA = (int*)(smem + 46080);          // 64
  float* sWp1 = (float*)(smem + 46336);        // 192
  float* sbp1 = (float*)(smem + 47104);        // 64
  float* sbp2 = (float*)(smem + 47360);        // 64
  float* sba1 = (float*)(smem + 47616);        // 256
  float* sba2 = (float*)(smem + 48640);        // 64

  const int t = threadIdx.x;
  const int w = t >> 6, l = t & 63, lq = l >> 4, ln = l & 15;
  const int d0 = 16*w + lq*4;

  if (t < 192) sWp1[t] = Wp1f[t];
  if (t < 64){ sbp1[t] = bp1f[t]; sbp2[t] = bp2[t]; sba2[t] = ba2[t]; }
  sba1[t] = ba1f[t];

  bfv8 Ape[2], A1[4][2], A2[8];
  #pragma unroll
  for (int kk = 0; kk < 2; ++kk)
    Ape[kk] = *(const bfv8*)(Wp2bf + (16*w + ln)*64 + kk*32 + lq*8);
  #pragma unroll
  for (int mt = 0; mt < 4; ++mt)
    #pragma unroll
    for (int kk = 0; kk < 2; ++kk)
      A1[mt][kk] = *(const bfv8*)(Wa1fbf + (64*w + mt*16 + ln)*64 + kk*32 + lq*8);
  #pragma unroll
  for (int kk = 0; kk < 8; ++kk)
    A2[kk] = *(const bfv8*)(Wa2bf + (16*w + ln)*256 + kk*32 + lq*8);
  __syncthreads();

  for (int ch = 0; ch < 2; ++ch) {
    const int p0 = blockIdx.x * 8 + ch * 4;
    const int b  = p0 >> 11;
    const int bN = b * 2048;
    if (t < 64) idxA[t] = idxb[p0*16 + t];
    qc[t] = qT[(p0 + (t>>6))*64 + (t & 63)];
    __syncthreads();
    if (t < 192) { int c = t >> 6, s = t & 63; int n = (p0 + (s>>4)) & 2047;
      r3[c*64 + s] = pq[(b*3+c)*NN + n] - ps[(b*3+c)*MM + idxA[s]]; }
    __syncthreads();
    { int s = t >> 2, iq = t & 3;
      float r0 = r3[s], r1 = r3[64+s], r2 = r3[128+s];
      u16 tmp[16];
      #pragma unroll
      for (int e = 0; e < 16; ++e) { int i = iq*16 + e;
        float v = sbp1[i] + sWp1[i*3]*r0 + sWp1[i*3+1]*r1 + sWp1[i*3+2]*r2;
        tmp[e] = f2bf(fmaxf(v, 0.f)); }
      *(bfv8*)&hp[s*72 + iq*16]     = *(const bfv8*)&tmp[0];
      *(bfv8*)&hp[s*72 + iq*16 + 8] = *(const bfv8*)&tmp[8];
    }
    __syncthreads();
    fv4 vvr[4];
    {
      fv4 pe[4];
      #pragma unroll
      for (int nt = 0; nt < 4; ++nt) {
        fv4 acc = {0.f,0.f,0.f,0.f};
        #pragma unroll
        for (int kk = 0; kk < 2; ++kk) {
          bfv8 bb = *(const bfv8*)&hp[(nt*16 + ln)*72 + kk*32 + lq*8];
          acc = MFMA16(Ape[kk], bb, acc, 0, 0, 0);
        }
        pe[nt] = acc;
      }
      fv4 bp2q = *(const fv4*)&sbp2[d0];
      #pragma unroll
      for (int nt = 0; nt < 4; ++nt) {
        int s = nt*16 + ln;
        int mi = idxA[s];
        fv4 kg = *(const fv4*)(kT + (bN + mi)*64 + d0);
        fv4 vg = *(const fv4*)(vT + (bN + mi)*64 + d0);
        fv4 qv = *(const fv4*)&qc[nt*64 + d0];
        fv4 pv = pe[nt] + bp2q;
        fv4 yv = qv - kg + pv;
        vvr[nt] = vg + pv;
        u16 yp[4];
        #pragma unroll
        for (int r = 0; r < 4; ++r) yp[r] = f2bf(yv[r]);
        *(bfv4*)&ylds[s*72 + d0] = *(const bfv4*)yp;
      }
    }
    __syncthreads();
    // GEMM1: a1 = Wa1f @ y, +ba1f, relu -> ha bf16 [s][h]
    #pragma unroll
    for (int nt = 0; nt < 4; ++nt) {
      int s = nt*16 + ln;
      bfv8 b0 = *(const bfv8*)&ylds[s*72 + lq*8];
      bfv8 b1 = *(const bfv8*)&ylds[s*72 + 32 + lq*8];
      #pragma unroll
      for (int mt = 0; mt < 4; ++mt) {
        fv4 acc = {0.f,0.f,0.f,0.f};
        acc = MFMA16(A1[mt][0], b0, acc, 0, 0, 0);
        acc = MFMA16(A1[mt][1], b1, acc, 0, 0, 0);
        int h0 = 64*w + mt*16 + lq*4;
        fv4 bq = *(const fv4*)&sba1[h0];
        u16 hv[4];
        #pragma unroll
        for (int r = 0; r < 4; ++r) hv[r] = f2bf(fmaxf(acc[r] + bq[r], 0.f));
        *(bfv4*)&ha[s*264 + h0] = *(const bfv4*)hv;
      }
    }
    __syncthreads();
    // GEMM2 + fused shuffle-softmax (k = ln within each 16-lane group)
    {
      fv4 acc2[4];
      #pragma unroll
      for (int nt = 0; nt < 4; ++nt) acc2[nt] = (fv4){0.f,0.f,0.f,0.f};
      #pragma unroll
      for (int kk = 0; kk < 8; ++kk) {
        #pragma unroll
        for (int nt = 0; nt < 4; ++nt) {
          bfv8 bb = *(const bfv8*)&ha[(nt*16 + ln)*264 + kk*32 + lq*8];
          acc2[nt] = MFMA16(A2[kk], bb, acc2[nt], 0, 0, 0);
        }
      }
      fv4 ba2q = *(const fv4*)&sba2[d0];
      #pragma unroll
      for (int nt = 0; nt < 4; ++nt) {
        fv4 a4 = acc2[nt] + ba2q;
        u16 o4[4];
        #pragma unroll
        for (int r = 0; r < 4; ++r) {
          float m = a4[r];
          m = fmaxf(m, __shfl_xor(m, 1, 64));
          m = fmaxf(m, __shfl_xor(m, 2, 64));
          m = fmaxf(m, __shfl_xor(m, 4, 64));
          m = fmaxf(m, __shfl_xor(m, 8, 64));
          float e = __expf(a4[r] - m);
          float se = e;
          se += __shfl_xor(se, 1, 64); se += __shfl_xor(se, 2, 64);
          se += __shfl_xor(se, 4, 64); se += __shfl_xor(se, 8, 64);
          float nu = e * vvr[nt][r];
          nu += __shfl_xor(nu, 1, 64); nu += __shfl_xor(nu, 2, 64);
          nu += __shfl_xor(nu, 4, 64); nu += __shfl_xor(nu, 8, 64);
          o4[r] = f2bf(nu / se);
        }
        if (ln == 0) *(bfv4*)&agg[(ch*4 + nt)*72 + d0] = *(const bfv4*)o4;
      }
    }
    __syncthreads();
  }
  // ---- fused epilogue: out = We @ agg + be + fq for this block's 8 pts ----
  {
    const int P0 = blockIdx.x * 8;
    const int b  = P0 >> 11;
    const int n0 = P0 & 2047;
    bfv8 EA[2][2];
    #pragma unroll
    for (int mt = 0; mt < 2; ++mt)
      #pragma unroll
      for (int kk = 0; kk < 2; ++kk)
        EA[mt][kk] = *(const bfv8*)(Webf + ((w*2 + mt)*16 + ln)*64 + kk*32 + lq*8);
    bfv8 b0 = {0,0,0,0,0,0,0,0}, b1 = {0,0,0,0,0,0,0,0};
    if (ln < 8) {
      b0 = *(const bfv8*)&agg[ln*72 + lq*8];
      b1 = *(const bfv8*)&agg[ln*72 + 32 + lq*8];
    }
    fv4 eacc[2];
    #pragma unroll
    for (int mt = 0; mt < 2; ++mt) {
      fv4 a = {0.f,0.f,0.f,0.f};
      a = MFMA16(EA[mt][0], b0, a, 0, 0, 0);
      a = MFMA16(EA[mt][1], b1, a, 0, 0, 0);
      eacc[mt] = a;
    }
    if (ln < 8) {
      #pragma unroll
      for (int mt = 0; mt < 2; ++mt) {
        int c0 = (w*2 + mt)*16 + lq*4;
        fv4 bev = *(const fv4*)&be[c0];
        #pragma unroll
        for (int r = 0; r < 4; ++r) {
          int c = c0 + r;
          int o = (b*128 + c)*2048 + n0 + ln;
          out[o] = eacc[mt][r] + bev[r] + fq[o];
        }
      }
    }
  }
}

// ---------------------------------------------------------------------------
extern "C" void kernel_launch(void* const* d_in, const int* in_sizes, int n_in,
                              void* d_out, int out_size, void* d_ws, size_t ws_size,
                              hipStream_t stream) {
  (void)in_sizes; (void)n_in; (void)out_size; (void)ws_size;
  const float* pq  = (const float*)d_in[0];
  const float* fq  = (const float*)d_in[1];
  const float* ps  = (const float*)d_in[2];
  const float* fs  = (const float*)d_in[3];
  const float* Wq  = (const float*)d_in[4];  const float* bq  = (const float*)d_in[5];
  const float* Wk  = (const float*)d_in[6];  const float* bk  = (const float*)d_in[7];
  const float* Wv  = (const float*)d_in[8];  const float* bv  = (const float*)d_in[9];
  const float* Wp1 = (const float*)d_in[10]; const float* bp1 = (const float*)d_in[11];
  const float* gp  = (const float*)d_in[12]; const float* btp = (const float*)d_in[13];
  const float* Wp2 = (const float*)d_in[14]; const float* bp2 = (const float*)d_in[15];
  const float* Wa1 = (const float*)d_in[16]; const float* ba1 = (const float*)d_in[17];
  const float* ga  = (const float*)d_in[18]; const float* bta = (const float*)d_in[19];
  const float* Wa2 = (const float*)d_in[20]; const float* ba2 = (const float*)d_in[21];
  const float* We  = (const float*)d_in[22]; const float* be  = (const float*)d_in[23];
  float* ws = (float*)d_ws;
  float* qT      = ws;                        // 524288
  float* kT      = ws + 524288;               // 524288
  float* vT      = ws + 1048576;              // 524288
  int*   idxb    = (int*)(ws + 1572864);      // 131072
  float* Wp1f    = ws + 1703936;              // 192
  float* bp1f    = ws + 1704128;              // 64
  float* ba1f    = ws + 1704192;              // 256
  float* G       = ws + 1704448;              // 4096
  float* ySum    = ws + 1708544;              // 64
  float* ySumP   = ws + 1708608;              // 65536 (1024*64)
  u16*   Wp2bf   = (u16*)(ws + 1774144);      // 4096 u16
  u16*   Wa2bf   = (u16*)(ws + 1776192);      // 16384 u16
  u16*   Wa1fbf  = (u16*)(ws + 1784384);      // 16384 u16
  u16*   Webf    = (u16*)(ws + 1792576);      // 8192 u16
  float* posPart = ws + 1796672;              // 24576 (2048*12)
  u16*   Gpart16 = (u16*)(ws + 1821248);      // 1024*4096 u16 = 8MB
  float* out     = (float*)d_out;

  k_front<<<2368, 256, 0, stream>>>(pq, ps, fq, fs, Wq, Wk, Wv, Wp2, Wa2, We,
                                    bq, bk, bv, Wp2bf, Wa2bf, Webf,
                                    qT, kT, vT, idxb, posPart);
  k_ystats<<<1024, 256, 0, stream>>>(pq, ps, qT, kT, idxb,
                                     Wp1, bp1, gp, btp, posPart, Wp2bf, bp2,
                                     Gpart16, ySumP, Wp1f, bp1f);
  k_gred<<<257, 256, 0, stream>>>(Gpart16, ySumP, G, ySum);
  k_attnfinal<<<256, 256, 0, stream>>>(Wa1, ba1, ga, bta, ySum, G, Wa1fbf, ba1f);
  k_main<<<1024, 256, 0, stream>>>(pq, ps, qT, kT, vT, idxb, Wp1f, bp1f, Wp2bf, bp2,
                                   Wa1fbf, ba1f, Wa2bf, ba2, Webf, be, fq, out);
}

// Round 12
// 244.624 us; speedup vs baseline: 1.0986x; 1.0986x over previous
//
#include <hip/hip_runtime.h>
#include <stdint.h>

#define NN 2048
#define MM 2048
#define NSAMP 131072   // B*N*K

typedef float  fv4 __attribute__((ext_vector_type(4)));
typedef short  bfv8 __attribute__((ext_vector_type(8)));
typedef short  bfv4 __attribute__((ext_vector_type(4)));
typedef unsigned short u16;
typedef unsigned long long u64;

__device__ inline u16 f2bf(float x){
  unsigned u = __float_as_uint(x);
  return (u16)((u + 0x7FFFu + ((u>>16)&1u)) >> 16);
}
__device__ inline float bf2f(u16 u){ return __uint_as_float(((unsigned)u)<<16); }
#define MFMA16 __builtin_amdgcn_mfma_f32_16x16x32_bf16

// ---------------------------------------------------------------------------
// prep: bf16-pack all weights (k-contiguous row-major) + psP float4
// ---------------------------------------------------------------------------
__global__ __launch_bounds__(256) void k_prep(
    const float* __restrict__ Wq, const float* __restrict__ Wk, const float* __restrict__ Wv,
    const float* __restrict__ Wp2, const float* __restrict__ Wa2, const float* __restrict__ We,
    const float* __restrict__ ps,
    u16* __restrict__ Wqbf, u16* __restrict__ Wkbf, u16* __restrict__ Wvbf,
    u16* __restrict__ Wp2bf, u16* __restrict__ Wa2bf, u16* __restrict__ Webf,
    fv4* __restrict__ psP) {
  int gid = blockIdx.x * 256 + threadIdx.x;   // grid 64*256 = 16384
  if (gid < 8192)  { Wqbf[gid] = f2bf(Wq[gid]); Wkbf[gid] = f2bf(Wk[gid]);
                     Wvbf[gid] = f2bf(Wv[gid]); Webf[gid] = f2bf(We[gid]); }
  if (gid < 4096)  Wp2bf[gid] = f2bf(Wp2[gid]);     // (D,D) row-major
  if (gid < 16384) Wa2bf[gid] = f2bf(Wa2[gid]);     // (D,H) row-major
  if (gid < 8192)  { int b = gid >> 11, m = gid & 2047;
    float x = ps[(b*3+0)*MM + m], y = ps[(b*3+1)*MM + m], z = ps[(b*3+2)*MM + m];
    fv4 p; p.x = x; p.y = y; p.z = z; p.w = x*x + y*y + z*z;
    psP[gid] = p; }
}

// ---------------------------------------------------------------------------
// q/k/v via MFMA with FUSED transpose+pack of fq/fs
// ---------------------------------------------------------------------------
__global__ __launch_bounds__(256) void k_qkv(
    const float* __restrict__ fq, const float* __restrict__ fs,
    const u16* __restrict__ Wqbf, const u16* __restrict__ Wkbf, const u16* __restrict__ Wvbf,
    const float* __restrict__ bq, const float* __restrict__ bk, const float* __restrict__ bv,
    float* __restrict__ qT, float* __restrict__ kT, float* __restrict__ vT) {
  __shared__ u16 tile[2][32 * 136];
  int bid = blockIdx.x;            // 256
  int b = bid >> 6, p0 = (bid & 63) * 32;
  int t = threadIdx.x;
  int w = t >> 6, l = t & 63, lq = l >> 4, ln = l & 15;
  {
    int cq = t >> 3, n4 = (t & 7) * 4;
    #pragma unroll
    for (int it = 0; it < 4; ++it) {
      int c = it * 32 + cq;
      fv4 vq = *(const fv4*)&fq[(b*128 + c)*2048 + p0 + n4];
      fv4 vs = *(const fv4*)&fs[(b*128 + c)*2048 + p0 + n4];
      #pragma unroll
      for (int j = 0; j < 4; ++j) {
        tile[0][(n4 + j)*136 + c] = f2bf(vq[j]);
        tile[1][(n4 + j)*136 + c] = f2bf(vs[j]);
      }
    }
  }
  bfv8 A[3][4];
  #pragma unroll
  for (int mat = 0; mat < 3; ++mat) {
    const u16* W = mat == 0 ? Wqbf : (mat == 1 ? Wkbf : Wvbf);
    #pragma unroll
    for (int kk = 0; kk < 4; ++kk)
      A[mat][kk] = *(const bfv8*)(W + (w*16 + ln)*128 + kk*32 + lq*8);
  }
  __syncthreads();
  fv4 acc[3][2];
  #pragma unroll
  for (int mat = 0; mat < 3; ++mat) {
    const u16* tl = tile[mat == 0 ? 0 : 1];
    #pragma unroll
    for (int nt = 0; nt < 2; ++nt) {
      fv4 a = {0.f,0.f,0.f,0.f};
      #pragma unroll
      for (int kk = 0; kk < 4; ++kk) {
        bfv8 bb = *(const bfv8*)&tl[(nt*16 + ln)*136 + kk*32 + lq*8];
        a = MFMA16(A[mat][kk], bb, a, 0, 0, 0);
      }
      acc[mat][nt] = a;
    }
  }
  #pragma unroll
  for (int mat = 0; mat < 3; ++mat) {
    float* dst = mat == 0 ? qT : (mat == 1 ? kT : vT);
    const float* bia = mat == 0 ? bq : (mat == 1 ? bk : bv);
    fv4 bq4 = *(const fv4*)&bia[w*16 + lq*4];
    #pragma unroll
    for (int nt = 0; nt < 2; ++nt) {
      fv4 o = acc[mat][nt] + bq4;
      *(fv4*)&dst[(b*NN + p0 + nt*16 + ln)*64 + w*16 + lq*4] = o;
    }
  }
}

// ---------------------------------------------------------------------------
// KNN with FUSED pos-moment accumulation (one 9-float partial per block)
// ---------------------------------------------------------------------------
__global__ __launch_bounds__(128) void k_knn(
    const float* __restrict__ pq, const fv4* __restrict__ psP,
    int* __restrict__ idxb, float* __restrict__ posPart) {
  __shared__ u64 cand[2][64 * 17];
  __shared__ float sacc[2][9];
  int t = threadIdx.x, w = t >> 6, lane = t & 63;
  int qi = blockIdx.x * 2 + w;       // 0..8191
  int b = qi >> 11, n = qi & 2047;
  const float* pqb = pq + b * 3 * NN;
  const fv4* psb = psP + b * 2048;
  float qx = pqb[n], qy = pqb[NN + n], qz = pqb[2 * NN + n];
  float qq = qx * qx + qy * qy + qz * qz;

  u64 A[16], Bv[16];
  #pragma unroll
  for (int j = 0; j < 16; ++j) {
    int m = lane + 64 * j;
    fv4 P = psb[m];
    float d2 = qq + P.w - 2.f * (qx * P.x + qy * P.y + qz * P.z);
    unsigned bu = __float_as_uint(d2);
    bu = (bu & 0x80000000u) ? ~bu : (bu | 0x80000000u);
    A[j] = (((u64)bu) << 32) | (unsigned)m;
  }
  #pragma unroll
  for (int j = 0; j < 16; ++j) {
    int m = lane + 64 * (j + 16);
    fv4 P = psb[m];
    float d2 = qq + P.w - 2.f * (qx * P.x + qy * P.y + qz * P.z);
    unsigned bu = __float_as_uint(d2);
    bu = (bu & 0x80000000u) ? ~bu : (bu | 0x80000000u);
    Bv[j] = (((u64)bu) << 32) | (unsigned)m;
  }
  #pragma unroll
  for (int k = 2; k <= 16; k <<= 1) {
    #pragma unroll
    for (int j = k >> 1; j > 0; j >>= 1) {
      #pragma unroll
      for (int i = 0; i < 16; ++i) {
        int l2 = i ^ j;
        if (l2 > i) {
          bool up = ((i & k) == 0);
          { u64 x = A[i], y = A[l2];
            bool sw = up ? (y < x) : (x < y);
            A[i] = sw ? y : x;  A[l2] = sw ? x : y; }
          { u64 x = Bv[i], y = Bv[l2];
            bool sw = up ? (y < x) : (x < y);
            Bv[i] = sw ? y : x; Bv[l2] = sw ? x : y; }
        }
      }
    }
  }
  #pragma unroll
  for (int i = 0; i < 16; ++i) {
    u64 y = Bv[15 - i];
    A[i] = A[i] < y ? A[i] : y;
  }
  #pragma unroll
  for (int j = 8; j > 0; j >>= 1) {
    #pragma unroll
    for (int i = 0; i < 16; ++i) {
      int l2 = i ^ j;
      if (l2 > i) {
        u64 x = A[i], y = A[l2];
        bool sw = (y < x);
        A[i] = sw ? y : x;  A[l2] = sw ? x : y;
      }
    }
  }
  #pragma unroll
  for (int i = 0; i < 16; ++i) cand[w][lane * 17 + i] = A[i];
  float s0=0.f,s1=0.f,s2=0.f,s3=0.f,s4=0.f,s5=0.f,s6=0.f,s7=0.f,s8=0.f;
  int head = 0;
  for (int r = 0; r < 16; ++r) {
    u64 v = (head < 16) ? cand[w][lane * 17 + head] : ~0ULL;
    u64 mv = v;
    #pragma unroll
    for (int off = 32; off > 0; off >>= 1) {
      u64 o = __shfl_xor(mv, off, 64);
      mv = o < mv ? o : mv;
    }
    if (v == mv) head++;
    unsigned m = (unsigned)(mv & 0xFFFFFFFFu);
    if (lane == 0) idxb[qi * 16 + r] = (int)m;
    fv4 P = psb[m];
    float r0 = qx - P.x, r1 = qy - P.y, r2 = qz - P.z;
    s0 += r0; s1 += r1; s2 += r2;
    s3 += r0*r0; s4 += r0*r1; s5 += r0*r2;
    s6 += r1*r1; s7 += r1*r2; s8 += r2*r2;
  }
  if (lane == 0) {
    sacc[w][0]=s0; sacc[w][1]=s1; sacc[w][2]=s2; sacc[w][3]=s3; sacc[w][4]=s4;
    sacc[w][5]=s5; sacc[w][6]=s6; sacc[w][7]=s7; sacc[w][8]=s8;
  }
  __syncthreads();
  if (t < 9) posPart[blockIdx.x * 12 + t] = sacc[0][t] + sacc[1][t];
}

// ---------------------------------------------------------------------------
// reduce pos partials (4096 records, PARALLEL) + fold pos-BN into Wp1/bp1
// ---------------------------------------------------------------------------
__global__ __launch_bounds__(256) void k_posfinal(
    const float* __restrict__ Wp1, const float* __restrict__ bp1,
    const float* __restrict__ gp, const float* __restrict__ btp,
    const float* __restrict__ posPart, float* __restrict__ Wp1f, float* __restrict__ bp1f) {
  __shared__ float red[4][9];
  __shared__ float st[9];
  int t = threadIdx.x;
  int w = t >> 6, lane = t & 63;
  float s[9];
  #pragma unroll
  for (int i = 0; i < 9; ++i) s[i] = 0.f;
  #pragma unroll
  for (int it = 0; it < 16; ++it) {
    const float* p = posPart + (it * 256 + t) * 12;
    fv4 a = *(const fv4*)p;
    fv4 b4 = *(const fv4*)(p + 4);
    float c8 = p[8];
    s[0]+=a.x; s[1]+=a.y; s[2]+=a.z; s[3]+=a.w;
    s[4]+=b4.x; s[5]+=b4.y; s[6]+=b4.z; s[7]+=b4.w;
    s[8]+=c8;
  }
  #pragma unroll
  for (int off = 32; off > 0; off >>= 1)
    #pragma unroll
    for (int i = 0; i < 9; ++i) s[i] += __shfl_xor(s[i], off, 64);
  if (lane == 0)
    #pragma unroll
    for (int i = 0; i < 9; ++i) red[w][i] = s[i];
  __syncthreads();
  if (t < 9) st[t] = red[0][t] + red[1][t] + red[2][t] + red[3][t];
  __syncthreads();
  if (t < 64) {
    int d = t;
    const float invN = 1.f / (float)NSAMP;
    float m0 = st[0]*invN, m1 = st[1]*invN, m2 = st[2]*invN;
    float C00 = st[3]*invN - m0*m0, C01 = st[4]*invN - m0*m1, C02 = st[5]*invN - m0*m2;
    float C11 = st[6]*invN - m1*m1, C12 = st[7]*invN - m1*m2, C22 = st[8]*invN - m2*m2;
    float w0 = Wp1[d*3], w1 = Wp1[d*3+1], w2 = Wp1[d*3+2];
    float mean = w0*m0 + w1*m1 + w2*m2 + bp1[d];
    float var = w0*w0*C00 + w1*w1*C11 + w2*w2*C22 + 2.f*(w0*w1*C01 + w0*w2*C02 + w1*w2*C12);
    float scale = gp[d] * rsqrtf(var + 1e-5f);
    Wp1f[d*3]   = scale * w0;
    Wp1f[d*3+1] = scale * w1;
    Wp1f[d*3+2] = scale * w2;
    bp1f[d] = btp[d] + scale * (bp1[d] - mean);
  }
}

// ---------------------------------------------------------------------------
// y-stats: Gram via MFMA. Grid 512 (16 pts/block)
// ---------------------------------------------------------------------------
__global__ __launch_bounds__(256) void k_ystats(
    const float* __restrict__ pq, const float* __restrict__ ps,
    const float* __restrict__ qT, const float* __restrict__ kT,
    const int* __restrict__ idxb,
    const float* __restrict__ Wp1f, const float* __restrict__ bp1f,
    const u16* __restrict__ Wp2bf, const float* __restrict__ bp2,
    float* __restrict__ Gpart, float* __restrict__ ySumPart) {
  __shared__ __align__(16) unsigned char smem[21760];
  u16*   hp   = (u16*)smem;                 // [64 s][72 i] bf16
  u16*   y2   = (u16*)(smem + 9216);        // [64 d][72 s] bf16
  float* r3   = (float*)(smem + 18432);     // 192
  float* qc   = (float*)(smem + 19200);     // 256
  int*   idxA = (int*)(smem + 20224);       // 64
  float* sWp1 = (float*)(smem + 20480);     // 192
  float* sbp1 = (float*)(smem + 21248);     // 64
  float* sbp2 = (float*)(smem + 21504);     // 64

  const int t = threadIdx.x;
  const int w = t >> 6, l = t & 63, lq = l >> 4, ln = l & 15;
  const int d0 = 16*w + lq*4;

  if (t < 192) sWp1[t] = Wp1f[t];
  if (t < 64){ sbp1[t] = bp1f[t]; sbp2[t] = bp2[t]; }

  bfv8 Ape[2];
  #pragma unroll
  for (int kk = 0; kk < 2; ++kk)
    Ape[kk] = *(const bfv8*)(Wp2bf + (16*w + ln)*64 + kk*32 + lq*8);

  fv4 gacc[4];
  #pragma unroll
  for (int nt = 0; nt < 4; ++nt) gacc[nt] = (fv4){0.f,0.f,0.f,0.f};
  float ys[4] = {0.f, 0.f, 0.f, 0.f};
  __syncthreads();

  for (int ch = 0; ch < 4; ++ch) {
    const int p0 = blockIdx.x * 16 + ch * 4;
    const int b  = p0 >> 11;
    const int bN = b * 2048;
    if (t < 64) idxA[t] = idxb[p0*16 + t];
    qc[t] = qT[(p0 + (t>>6))*64 + (t & 63)];
    __syncthreads();
    if (t < 192) { int c = t >> 6, s = t & 63; int n = (p0 + (s>>4)) & 2047;
      r3[c*64 + s] = pq[(b*3+c)*NN + n] - ps[(b*3+c)*MM + idxA[s]]; }
    __syncthreads();
    { int s = t >> 2, iq = t & 3;
      float r0 = r3[s], r1 = r3[64+s], r2 = r3[128+s];
      u16 tmp[16];
      #pragma unroll
      for (int e = 0; e < 16; ++e) { int i = iq*16 + e;
        float v = sbp1[i] + sWp1[i*3]*r0 + sWp1[i*3+1]*r1 + sWp1[i*3+2]*r2;
        tmp[e] = f2bf(fmaxf(v, 0.f)); }
      *(bfv8*)&hp[s*72 + iq*16]     = *(const bfv8*)&tmp[0];
      *(bfv8*)&hp[s*72 + iq*16 + 8] = *(const bfv8*)&tmp[8];
    }
    __syncthreads();
    {
      fv4 pe[4];
      #pragma unroll
      for (int nt = 0; nt < 4; ++nt) {
        fv4 acc = {0.f,0.f,0.f,0.f};
        #pragma unroll
        for (int kk = 0; kk < 2; ++kk) {
          bfv8 bb = *(const bfv8*)&hp[(nt*16 + ln)*72 + kk*32 + lq*8];
          acc = MFMA16(Ape[kk], bb, acc, 0, 0, 0);
        }
        pe[nt] = acc;
      }
      fv4 bp2q = *(const fv4*)&sbp2[d0];
      #pragma unroll
      for (int nt = 0; nt < 4; ++nt) {
        int s = nt*16 + ln;
        int mi = idxA[s];
        fv4 kg = *(const fv4*)(kT + (bN + mi)*64 + d0);
        fv4 qv = *(const fv4*)&qc[nt*64 + d0];
        fv4 yv = qv - kg + pe[nt] + bp2q;
        #pragma unroll
        for (int r = 0; r < 4; ++r) { y2[(d0 + r)*72 + s] = f2bf(yv[r]); ys[r] += yv[r]; }
      }
    }
    __syncthreads();
    #pragma unroll
    for (int kk = 0; kk < 2; ++kk) {
      bfv8 aa = *(const bfv8*)&y2[(16*w + ln)*72 + kk*32 + lq*8];
      #pragma unroll
      for (int nt = 0; nt < 4; ++nt) {
        bfv8 bb = *(const bfv8*)&y2[(nt*16 + ln)*72 + kk*32 + lq*8];
        gacc[nt] = MFMA16(aa, bb, gacc[nt], 0, 0, 0);
      }
    }
    __syncthreads();
  }
  #pragma unroll
  for (int nt = 0; nt < 4; ++nt)
    #pragma unroll
    for (int r = 0; r < 4; ++r)
      Gpart[blockIdx.x*4096 + (16*w + lq*4 + r)*64 + nt*16 + ln] = gacc[nt][r];
  #pragma unroll
  for (int off = 1; off <= 8; off <<= 1) {
    #pragma unroll
    for (int r = 0; r < 4; ++r) ys[r] += __shfl_xor(ys[r], off, 64);
  }
  if (ln == 0) {
    #pragma unroll
    for (int r = 0; r < 4; ++r) ySumPart[blockIdx.x*64 + d0 + r] = ys[r];
  }
}

// ---------------------------------------------------------------------------
// reduce Gram / ySum partials (512 blocks)
// ---------------------------------------------------------------------------
__global__ __launch_bounds__(256) void k_gred(
    const float* __restrict__ Gpart, const float* __restrict__ ySumPart,
    float* __restrict__ G, float* __restrict__ ySum) {
  int bid = blockIdx.x, t = threadIdx.x;   // grid 17
  if (bid < 16) {
    int j = bid*256 + t;
    float s = 0.f;
    for (int p = 0; p < 512; ++p) s += Gpart[p*4096 + j];
    G[j] = s;
  } else if (t < 64) {
    float s = 0.f;
    for (int p = 0; p < 512; ++p) s += ySumPart[p*64 + t];
    ySum[t] = s;
  }
}

// ---------------------------------------------------------------------------
// fold attn-BN into Wa1/ba1; emit bf16 Wa1f
// ---------------------------------------------------------------------------
__global__ __launch_bounds__(256) void k_attnfinal(
    const float* __restrict__ Wa1, const float* __restrict__ ba1,
    const float* __restrict__ ga, const float* __restrict__ bta,
    const float* __restrict__ ySum, const float* __restrict__ G,
    u16* __restrict__ Wa1fbf, float* __restrict__ ba1f) {
  __shared__ float red[256];
  __shared__ float mu[64];
  __shared__ float sc[1];
  int h = blockIdx.x, t = threadIdx.x;
  const float invN = 1.f / (float)NSAMP;
  if (t < 64) mu[t] = ySum[t] * invN;
  __syncthreads();
  float acc = 0.f;
  #pragma unroll
  for (int e = 0; e < 16; ++e) {
    int pi = t*16 + e, i = pi >> 6, j = pi & 63;
    float cov = G[pi]*invN - mu[i]*mu[j];
    acc += Wa1[h*64 + i] * Wa1[h*64 + j] * cov;
  }
  red[t] = acc;
  __syncthreads();
  for (int s = 128; s > 0; s >>= 1) { if (t < s) red[t] += red[t + s]; __syncthreads(); }
  float var = red[0];
  __syncthreads();
  red[t] = (t < 64) ? Wa1[h*64 + t] * mu[t] : 0.f;
  __syncthreads();
  for (int s = 128; s > 0; s >>= 1) { if (t < s) red[t] += red[t + s]; __syncthreads(); }
  if (t == 0) {
    float mean  = red[0] + ba1[h];
    float scale = ga[h] * rsqrtf(var + 1e-5f);
    sc[0] = scale;
    ba1f[h] = bta[h] + scale * (ba1[h] - mean);
  }
  __syncthreads();
  if (t < 64) Wa1fbf[h*64 + t] = f2bf(sc[0] * Wa1[h*64 + t]);
}

// ---------------------------------------------------------------------------
// main fused kernel (recompute) + fused epilogue. grid 512, 16 pts/block.
// ---------------------------------------------------------------------------
__global__ __launch_bounds__(256) void k_main(
    const float* __restrict__ pq, const float* __restrict__ ps,
    const float* __restrict__ qT, const float* __restrict__ kT, const float* __restrict__ vT,
    const int* __restrict__ idxb,
    const float* __restrict__ Wp1f, const float* __restrict__ bp1f,
    const u16* __restrict__ Wp2bf, const float* __restrict__ bp2,
    const u16* __restrict__ Wa1fbf, const float* __restrict__ ba1f,
    const u16* __restrict__ Wa2bf, const float* __restrict__ ba2,
    const u16* __restrict__ Webf, const float* __restrict__ be,
    const float* __restrict__ fq,
    u16* __restrict__ aggbf, float* __restrict__ out) {
  __shared__ __align__(16) unsigned char smem[65024];
  u16*   hp   = (u16*)smem;                    // [64 s][72 i] bf16 (aliases ha)
  u16*   ha   = (u16*)smem;                    // [64 s][264 h] bf16
  u16*   ylds = (u16*)(smem + 33792);          // [64 s][72 d] bf16 (aliases at)
  float* at   = (float*)(smem + 33792);        // [64 s][68 d] f32
  u16*   vt   = (u16*)(smem + 51200);          // [64 s][72 d] bf16
  float* r3   = (float*)(smem + 60416);        // 192
  float* qc   = (float*)(smem + 61184);        // 256
  int*   idxA = (int*)(smem + 62208);          // 64
  float* sWp1 = (float*)(smem + 62464);        // 192
  float* sbp1 = (float*)(smem + 63232);        // 64
  float* sbp2 = (float*)(smem + 63488);        // 64
  float* sba1 = (float*)(smem + 63744);        // 256
  float* sba2 = (float*)(smem + 64768);        // 64

  const int t = threadIdx.x;
  const int w = t >> 6, l = t & 63, lq = l >> 4, ln = l & 15;
  const int d0 = 16*w + lq*4;

  if (t < 192) sWp1[t] = Wp1f[t];
  if (t < 64){ sbp1[t] = bp1f[t]; sbp2[t] = bp2[t]; sba2[t] = ba2[t]; }
  sba1[t] = ba1f[t];

  bfv8 Ape[2], A1[4][2], A2[8];
  #pragma unroll
  for (int kk = 0; kk < 2; ++kk)
    Ape[kk] = *(const bfv8*)(Wp2bf + (16*w + ln)*64 + kk*32 + lq*8);
  #pragma unroll
  for (int mt = 0; mt < 4; ++mt)
    #pragma unroll
    for (int kk = 0; kk < 2; ++kk)
      A1[mt][kk] = *(const bfv8*)(Wa1fbf + (64*w + mt*16 + ln)*64 + kk*32 + lq*8);
  #pragma unroll
  for (int kk = 0; kk < 8; ++kk)
    A2[kk] = *(const bfv8*)(Wa2bf + (16*w + ln)*256 + kk*32 + lq*8);
  __syncthreads();

  for (int ch = 0; ch < 4; ++ch) {
    const int p0 = blockIdx.x * 16 + ch * 4;
    const int b  = p0 >> 11;
    const int bN = b * 2048;
    if (t < 64) idxA[t] = idxb[p0*16 + t];
    qc[t] = qT[(p0 + (t>>6))*64 + (t & 63)];
    __syncthreads();
    if (t < 192) { int c = t >> 6, s = t & 63; int n = (p0 + (s>>4)) & 2047;
      r3[c*64 + s] = pq[(b*3+c)*NN + n] - ps[(b*3+c)*MM + idxA[s]]; }
    __syncthreads();
    { int s = t >> 2, iq = t & 3;
      float r0 = r3[s], r1 = r3[64+s], r2 = r3[128+s];
      u16 tmp[16];
      #pragma unroll
      for (int e = 0; e < 16; ++e) { int i = iq*16 + e;
        float v = sbp1[i] + sWp1[i*3]*r0 + sWp1[i*3+1]*r1 + sWp1[i*3+2]*r2;
        tmp[e] = f2bf(fmaxf(v, 0.f)); }
      *(bfv8*)&hp[s*72 + iq*16]     = *(const bfv8*)&tmp[0];
      *(bfv8*)&hp[s*72 + iq*16 + 8] = *(const bfv8*)&tmp[8];
    }
    __syncthreads();
    {
      fv4 pe[4];
      #pragma unroll
      for (int nt = 0; nt < 4; ++nt) {
        fv4 acc = {0.f,0.f,0.f,0.f};
        #pragma unroll
        for (int kk = 0; kk < 2; ++kk) {
          bfv8 bb = *(const bfv8*)&hp[(nt*16 + ln)*72 + kk*32 + lq*8];
          acc = MFMA16(Ape[kk], bb, acc, 0, 0, 0);
        }
        pe[nt] = acc;
      }
      fv4 bp2q = *(const fv4*)&sbp2[d0];
      #pragma unroll
      for (int nt = 0; nt < 4; ++nt) {
        int s = nt*16 + ln;
        int mi = idxA[s];
        fv4 kg = *(const fv4*)(kT + (bN + mi)*64 + d0);
        fv4 vg = *(const fv4*)(vT + (bN + mi)*64 + d0);
        fv4 qv = *(const fv4*)&qc[nt*64 + d0];
        fv4 pv = pe[nt] + bp2q;
        fv4 yv = qv - kg + pv;
        fv4 vv = vg + pv;
        u16 yp[4], vp[4];
        #pragma unroll
        for (int r = 0; r < 4; ++r) { yp[r] = f2bf(yv[r]); vp[r] = f2bf(vv[r]); }
        *(bfv4*)&ylds[s*72 + d0] = *(const bfv4*)yp;
        *(bfv4*)&vt[s*72 + d0]   = *(const bfv4*)vp;
      }
    }
    __syncthreads();
    #pragma unroll
    for (int nt = 0; nt < 4; ++nt) {
      int s = nt*16 + ln;
      bfv8 b0 = *(const bfv8*)&ylds[s*72 + lq*8];
      bfv8 b1 = *(const bfv8*)&ylds[s*72 + 32 + lq*8];
      #pragma unroll
      for (int mt = 0; mt < 4; ++mt) {
        fv4 acc = {0.f,0.f,0.f,0.f};
        acc = MFMA16(A1[mt][0], b0, acc, 0, 0, 0);
        acc = MFMA16(A1[mt][1], b1, acc, 0, 0, 0);
        int h0 = 64*w + mt*16 + lq*4;
        fv4 bq = *(const fv4*)&sba1[h0];
        u16 hv[4];
        #pragma unroll
        for (int r = 0; r < 4; ++r) hv[r] = f2bf(fmaxf(acc[r] + bq[r], 0.f));
        *(bfv4*)&ha[s*264 + h0] = *(const bfv4*)hv;
      }
    }
    __syncthreads();
    {
      fv4 acc2[4];
      #pragma unroll
      for (int nt = 0; nt < 4; ++nt) acc2[nt] = (fv4){0.f,0.f,0.f,0.f};
      #pragma unroll
      for (int kk = 0; kk < 8; ++kk) {
        #pragma unroll
        for (int nt = 0; nt < 4; ++nt) {
          bfv8 bb = *(const bfv8*)&ha[(nt*16 + ln)*264 + kk*32 + lq*8];
          acc2[nt] = MFMA16(A2[kk], bb, acc2[nt], 0, 0, 0);
        }
      }
      fv4 ba2q = *(const fv4*)&sba2[d0];
      #pragma unroll
      for (int nt = 0; nt < 4; ++nt) {
        int s = nt*16 + ln;
        fv4 o = acc2[nt] + ba2q;
        *(fv4*)&at[s*68 + d0] = o;
      }
    }
    __syncthreads();
    {
      int dd = t & 63, pt = t >> 6;
      float a[16];
      #pragma unroll
      for (int k = 0; k < 16; ++k) a[k] = at[(pt*16 + k)*68 + dd];
      float mx = a[0];
      #pragma unroll
      for (int k = 1; k < 16; ++k) mx = fmaxf(mx, a[k]);
      float sum = 0.f, num = 0.f;
      #pragma unroll
      for (int k = 0; k < 16; ++k) {
        float e = __expf(a[k] - mx);
        sum += e;
        num += e * bf2f(vt[(pt*16 + k)*72 + dd]);
      }
      aggbf[(p0 + pt)*64 + dd] = f2bf(num / sum);
    }
    __syncthreads();
  }
  // ---- fused epilogue: out = We @ agg + be + fq for this block's 16 pts ----
  {
    const int P0 = blockIdx.x * 16;
    const int b  = P0 >> 11;
    const int n0 = P0 & 2047;
    bfv8 EA[2][2];
    #pragma unroll
    for (int mt = 0; mt < 2; ++mt)
      #pragma unroll
      for (int kk = 0; kk < 2; ++kk)
        EA[mt][kk] = *(const bfv8*)(Webf + ((w*2 + mt)*16 + ln)*64 + kk*32 + lq*8);
    const u16* bp = aggbf + (P0 + ln)*64;
    bfv8 b0 = *(const bfv8*)(bp + lq*8);
    bfv8 b1 = *(const bfv8*)(bp + 32 + lq*8);
    fv4 eacc[2];
    #pragma unroll
    for (int mt = 0; mt < 2; ++mt) {
      fv4 a = {0.f,0.f,0.f,0.f};
      a = MFMA16(EA[mt][0], b0, a, 0, 0, 0);
      a = MFMA16(EA[mt][1], b1, a, 0, 0, 0);
      eacc[mt] = a;
    }
    #pragma unroll
    for (int mt = 0; mt < 2; ++mt) {
      int c0 = (w*2 + mt)*16 + lq*4;
      fv4 bev = *(const fv4*)&be[c0];
      #pragma unroll
      for (int r = 0; r < 4; ++r) {
        int c = c0 + r;
        int o = (b*128 + c)*2048 + n0 + ln;
        out[o] = eacc[mt][r] + bev[r] + fq[o];
      }
    }
  }
}

// ---------------------------------------------------------------------------
extern "C" void kernel_launch(void* const* d_in, const int* in_sizes, int n_in,
                              void* d_out, int out_size, void* d_ws, size_t ws_size,
                              hipStream_t stream) {
  (void)in_sizes; (void)n_in; (void)out_size; (void)ws_size;
  const float* pq  = (const float*)d_in[0];
  const float* fq  = (const float*)d_in[1];
  const float* ps  = (const float*)d_in[2];
  const float* fs  = (const float*)d_in[3];
  const float* Wq  = (const float*)d_in[4];  const float* bq  = (const float*)d_in[5];
  const float* Wk  = (const float*)d_in[6];  const float* bk  = (const float*)d_in[7];
  const float* Wv  = (const float*)d_in[8];  const float* bv  = (const float*)d_in[9];
  const float* Wp1 = (const float*)d_in[10]; const float* bp1 = (const float*)d_in[11];
  const float* gp  = (const float*)d_in[12]; const float* btp = (const float*)d_in[13];
  const float* Wp2 = (const float*)d_in[14]; const float* bp2 = (const float*)d_in[15];
  const float* Wa1 = (const float*)d_in[16]; const float* ba1 = (const float*)d_in[17];
  const float* ga  = (const float*)d_in[18]; const float* bta = (const float*)d_in[19];
  const float* Wa2 = (const float*)d_in[20]; const float* ba2 = (const float*)d_in[21];
  const float* We  = (const float*)d_in[22]; const float* be  = (const float*)d_in[23];
  float* ws = (float*)d_ws;
  float* qT    = ws;                         // 524288
  float* kT    = ws + 524288;                // 524288
  float* vT    = ws + 1048576;               // 524288
  u16*   aggbf = (u16*)(ws + 1572864);       // 524288 fl region (1MB used)
  int*   idxb  = (int*)(ws + 2097152);       // 131072
  u16*   Wqbf  = (u16*)(ws + 2228224);       // 4096 fl each
  u16*   Wkbf  = (u16*)(ws + 2232320);
  u16*   Wvbf  = (u16*)(ws + 2236416);
  u16*   Webf  = (u16*)(ws + 2240512);
  fv4*   psP   = (fv4*)(ws + 2244608);       // 131072 fl
  float* Wp1f  = ws + 2375680;               // 192
  float* bp1f  = ws + 2375872;               // 64
  float* ba1f  = ws + 2375936;               // 256
  float* G     = ws + 2376192;               // 4096
  float* ySum  = ws + 2380288;               // 64
  float* ySumP = ws + 2380352;               // 32768 (512*64)
  u16*   Wp2bf  = (u16*)(ws + 2413120);      // 2048 fl
  u16*   Wa2bf  = (u16*)(ws + 2415168);      // 8192 fl
  u16*   Wa1fbf = (u16*)(ws + 2423360);      // 8192 fl
  float* posPart = ws + 2431552;             // 49152 (4096*12)
  float* Gpart   = ws + 2480704;             // 2097152 (512*4096)
  float* out   = (float*)d_out;

  k_prep<<<64, 256, 0, stream>>>(Wq, Wk, Wv, Wp2, Wa2, We, ps,
                                 Wqbf, Wkbf, Wvbf, Wp2bf, Wa2bf, Webf, psP);
  k_qkv<<<256, 256, 0, stream>>>(fq, fs, Wqbf, Wkbf, Wvbf, bq, bk, bv, qT, kT, vT);
  k_knn<<<4096, 128, 0, stream>>>(pq, psP, idxb, posPart);
  k_posfinal<<<1, 256, 0, stream>>>(Wp1, bp1, gp, btp, posPart, Wp1f, bp1f);
  k_ystats<<<512, 256, 0, stream>>>(pq, ps, qT, kT, idxb, Wp1f, bp1f, Wp2bf, bp2,
                                    Gpart, ySumP);
  k_gred<<<17, 256, 0, stream>>>(Gpart, ySumP, G, ySum);
  k_attnfinal<<<256, 256, 0, stream>>>(Wa1, ba1, ga, bta, ySum, G, Wa1fbf, ba1f);
  k_main<<<512, 256, 0, stream>>>(pq, ps, qT, kT, vT, idxb, Wp1f, bp1f, Wp2bf, bp2,
                                  Wa1fbf, ba1f, Wa2bf, ba2, Webf, be, fq, aggbf, out);
}

// Round 13
// 236.037 us; speedup vs baseline: 1.1386x; 1.0364x over previous
//
#include <hip/hip_runtime.h>
#include <stdint.h>

#define NN 2048
#define MM 2048
#define NSAMP 131072   // B*N*K

typedef float  fv4 __attribute__((ext_vector_type(4)));
typedef short  bfv8 __attribute__((ext_vector_type(8)));
typedef short  bfv4 __attribute__((ext_vector_type(4)));
typedef unsigned short u16;
typedef unsigned long long u64;

__device__ inline u16 f2bf(float x){
  unsigned u = __float_as_uint(x);
  return (u16)((u + 0x7FFFu + ((u>>16)&1u)) >> 16);
}
__device__ inline float bf2f(u16 u){ return __uint_as_float(((unsigned)u)<<16); }
#define MFMA16 __builtin_amdgcn_mfma_f32_16x16x32_bf16

// ---------------------------------------------------------------------------
// prep: bf16-pack all weights (k-contiguous row-major) + psP float4
// ---------------------------------------------------------------------------
__global__ __launch_bounds__(256) void k_prep(
    const float* __restrict__ Wq, const float* __restrict__ Wk, const float* __restrict__ Wv,
    const float* __restrict__ Wp2, const float* __restrict__ Wa2, const float* __restrict__ We,
    const float* __restrict__ ps,
    u16* __restrict__ Wqbf, u16* __restrict__ Wkbf, u16* __restrict__ Wvbf,
    u16* __restrict__ Wp2bf, u16* __restrict__ Wa2bf, u16* __restrict__ Webf,
    fv4* __restrict__ psP) {
  int gid = blockIdx.x * 256 + threadIdx.x;   // grid 64*256 = 16384
  if (gid < 8192)  { Wqbf[gid] = f2bf(Wq[gid]); Wkbf[gid] = f2bf(Wk[gid]);
                     Wvbf[gid] = f2bf(Wv[gid]); Webf[gid] = f2bf(We[gid]); }
  if (gid < 4096)  Wp2bf[gid] = f2bf(Wp2[gid]);     // (D,D) row-major
  if (gid < 16384) Wa2bf[gid] = f2bf(Wa2[gid]);     // (D,H) row-major
  if (gid < 8192)  { int b = gid >> 11, m = gid & 2047;
    float x = ps[(b*3+0)*MM + m], y = ps[(b*3+1)*MM + m], z = ps[(b*3+2)*MM + m];
    fv4 p; p.x = x; p.y = y; p.z = z; p.w = x*x + y*y + z*z;
    psP[gid] = p; }
}

// ---------------------------------------------------------------------------
// q/k/v via MFMA with FUSED transpose+pack of fq/fs
// ---------------------------------------------------------------------------
__global__ __launch_bounds__(256) void k_qkv(
    const float* __restrict__ fq, const float* __restrict__ fs,
    const u16* __restrict__ Wqbf, const u16* __restrict__ Wkbf, const u16* __restrict__ Wvbf,
    const float* __restrict__ bq, const float* __restrict__ bk, const float* __restrict__ bv,
    float* __restrict__ qT, float* __restrict__ kT, float* __restrict__ vT) {
  __shared__ u16 tile[2][32 * 136];
  int bid = blockIdx.x;            // 256
  int b = bid >> 6, p0 = (bid & 63) * 32;
  int t = threadIdx.x;
  int w = t >> 6, l = t & 63, lq = l >> 4, ln = l & 15;
  {
    int cq = t >> 3, n4 = (t & 7) * 4;
    #pragma unroll
    for (int it = 0; it < 4; ++it) {
      int c = it * 32 + cq;
      fv4 vq = *(const fv4*)&fq[(b*128 + c)*2048 + p0 + n4];
      fv4 vs = *(const fv4*)&fs[(b*128 + c)*2048 + p0 + n4];
      #pragma unroll
      for (int j = 0; j < 4; ++j) {
        tile[0][(n4 + j)*136 + c] = f2bf(vq[j]);
        tile[1][(n4 + j)*136 + c] = f2bf(vs[j]);
      }
    }
  }
  bfv8 A[3][4];
  #pragma unroll
  for (int mat = 0; mat < 3; ++mat) {
    const u16* W = mat == 0 ? Wqbf : (mat == 1 ? Wkbf : Wvbf);
    #pragma unroll
    for (int kk = 0; kk < 4; ++kk)
      A[mat][kk] = *(const bfv8*)(W + (w*16 + ln)*128 + kk*32 + lq*8);
  }
  __syncthreads();
  fv4 acc[3][2];
  #pragma unroll
  for (int mat = 0; mat < 3; ++mat) {
    const u16* tl = tile[mat == 0 ? 0 : 1];
    #pragma unroll
    for (int nt = 0; nt < 2; ++nt) {
      fv4 a = {0.f,0.f,0.f,0.f};
      #pragma unroll
      for (int kk = 0; kk < 4; ++kk) {
        bfv8 bb = *(const bfv8*)&tl[(nt*16 + ln)*136 + kk*32 + lq*8];
        a = MFMA16(A[mat][kk], bb, a, 0, 0, 0);
      }
      acc[mat][nt] = a;
    }
  }
  #pragma unroll
  for (int mat = 0; mat < 3; ++mat) {
    float* dst = mat == 0 ? qT : (mat == 1 ? kT : vT);
    const float* bia = mat == 0 ? bq : (mat == 1 ? bk : bv);
    fv4 bq4 = *(const fv4*)&bia[w*16 + lq*4];
    #pragma unroll
    for (int nt = 0; nt < 2; ++nt) {
      fv4 o = acc[mat][nt] + bq4;
      *(fv4*)&dst[(b*NN + p0 + nt*16 + ln)*64 + w*16 + lq*4] = o;
    }
  }
}

// ---------------------------------------------------------------------------
// KNN: per-lane bitonic top-16 of 32; extraction via FOUR 16-lane groups
// (4-step shuffle chain, register head-tracking, NO cand LDS); one final
// lane-bitonic sort of the 64 group-winners -> exact global top-16 asc.
// Fused pos-moment accumulation (winners are wave-uniform).
// ---------------------------------------------------------------------------
__global__ __launch_bounds__(128) void k_knn(
    const float* __restrict__ pq, const fv4* __restrict__ psP,
    int* __restrict__ idxb, float* __restrict__ posPart) {
  __shared__ u64 winLDS[2][64];
  __shared__ float sacc[2][9];
  int t = threadIdx.x, w = t >> 6, lane = t & 63;
  int qi = blockIdx.x * 2 + w;       // 0..8191
  int b = qi >> 11, n = qi & 2047;
  const float* pqb = pq + b * 3 * NN;
  const fv4* psb = psP + b * 2048;
  float qx = pqb[n], qy = pqb[NN + n], qz = pqb[2 * NN + n];
  float qq = qx * qx + qy * qy + qz * qz;

  u64 A[16], Bv[16];
  #pragma unroll
  for (int j = 0; j < 16; ++j) {
    int m = lane + 64 * j;
    fv4 P = psb[m];
    float d2 = qq + P.w - 2.f * (qx * P.x + qy * P.y + qz * P.z);
    unsigned bu = __float_as_uint(d2);
    bu = (bu & 0x80000000u) ? ~bu : (bu | 0x80000000u);
    A[j] = (((u64)bu) << 32) | (unsigned)m;
  }
  #pragma unroll
  for (int j = 0; j < 16; ++j) {
    int m = lane + 64 * (j + 16);
    fv4 P = psb[m];
    float d2 = qq + P.w - 2.f * (qx * P.x + qy * P.y + qz * P.z);
    unsigned bu = __float_as_uint(d2);
    bu = (bu & 0x80000000u) ? ~bu : (bu | 0x80000000u);
    Bv[j] = (((u64)bu) << 32) | (unsigned)m;
  }
  // bitonic sort both halves ascending
  #pragma unroll
  for (int k = 2; k <= 16; k <<= 1) {
    #pragma unroll
    for (int j = k >> 1; j > 0; j >>= 1) {
      #pragma unroll
      for (int i = 0; i < 16; ++i) {
        int l2 = i ^ j;
        if (l2 > i) {
          bool up = ((i & k) == 0);
          { u64 x = A[i], y = A[l2];
            bool sw = up ? (y < x) : (x < y);
            A[i] = sw ? y : x;  A[l2] = sw ? x : y; }
          { u64 x = Bv[i], y = Bv[l2];
            bool sw = up ? (y < x) : (x < y);
            Bv[i] = sw ? y : x; Bv[l2] = sw ? x : y; }
        }
      }
    }
  }
  // keep-16 of the lane's 32: A[i] = min(A[i], Bv[15-i]); 4-stage clean
  #pragma unroll
  for (int i = 0; i < 16; ++i) {
    u64 y = Bv[15 - i];
    A[i] = A[i] < y ? A[i] : y;
  }
  #pragma unroll
  for (int j = 8; j > 0; j >>= 1) {
    #pragma unroll
    for (int i = 0; i < 16; ++i) {
      int l2 = i ^ j;
      if (l2 > i) {
        u64 x = A[i], y = A[l2];
        bool sw = (y < x);
        A[i] = sw ? y : x;  A[l2] = sw ? x : y;
      }
    }
  }
  // group extraction: 4 groups of 16 lanes, each pops its group-min 16 times.
  // Register head-tracking: on pop, shift list down and feed MAX at tail.
  for (int r = 0; r < 16; ++r) {
    u64 v = A[0];
    u64 mv = v;
    #pragma unroll
    for (int off = 1; off <= 8; off <<= 1) {
      u64 o = __shfl_xor(mv, off, 64);
      mv = o < mv ? o : mv;
    }
    bool pop = (v == mv);          // exactly one lane per group (idx unique)
    #pragma unroll
    for (int i = 0; i < 15; ++i) A[i] = pop ? A[i+1] : A[i];
    A[15] = pop ? ~0ULL : A[15];
    if ((lane & 15) == 0) winLDS[w][(lane >> 4) * 16 + r] = mv;
  }
  // full lane-bitonic sort of the 64 group-winners (1 elem/lane, ascending)
  u64 e = winLDS[w][lane];
  #pragma unroll
  for (int k = 2; k <= 64; k <<= 1) {
    #pragma unroll
    for (int j = k >> 1; j > 0; j >>= 1) {
      u64 x = __shfl_xor(e, j, 64);
      u64 lo = e < x ? e : x, hi = e < x ? x : e;
      bool up = ((lane & k) == 0);                 // k=64 -> all ascending
      bool takeLo = (((lane & j) == 0) == up);
      e = takeLo ? lo : hi;
    }
  }
  if (lane < 16) idxb[qi * 16 + lane] = (int)(e & 0xFFFFFFFFu);
  winLDS[w][lane] = e;
  // pos moments over the 16 winners (wave-uniform; every lane identical sums)
  float s0=0.f,s1=0.f,s2=0.f,s3=0.f,s4=0.f,s5=0.f,s6=0.f,s7=0.f,s8=0.f;
  #pragma unroll 4
  for (int r = 0; r < 16; ++r) {
    unsigned m = (unsigned)(winLDS[w][r] & 0xFFFFFFFFu);
    fv4 P = psb[m];
    float r0 = qx - P.x, r1 = qy - P.y, r2 = qz - P.z;
    s0 += r0; s1 += r1; s2 += r2;
    s3 += r0*r0; s4 += r0*r1; s5 += r0*r2;
    s6 += r1*r1; s7 += r1*r2; s8 += r2*r2;
  }
  if (lane == 0) {
    sacc[w][0]=s0; sacc[w][1]=s1; sacc[w][2]=s2; sacc[w][3]=s3; sacc[w][4]=s4;
    sacc[w][5]=s5; sacc[w][6]=s6; sacc[w][7]=s7; sacc[w][8]=s8;
  }
  __syncthreads();
  if (t < 9) posPart[blockIdx.x * 12 + t] = sacc[0][t] + sacc[1][t];
}

// ---------------------------------------------------------------------------
// reduce pos partials (4096 records, PARALLEL) + fold pos-BN into Wp1/bp1
// ---------------------------------------------------------------------------
__global__ __launch_bounds__(256) void k_posfinal(
    const float* __restrict__ Wp1, const float* __restrict__ bp1,
    const float* __restrict__ gp, const float* __restrict__ btp,
    const float* __restrict__ posPart, float* __restrict__ Wp1f, float* __restrict__ bp1f) {
  __shared__ float red[4][9];
  __shared__ float st[9];
  int t = threadIdx.x;
  int w = t >> 6, lane = t & 63;
  float s[9];
  #pragma unroll
  for (int i = 0; i < 9; ++i) s[i] = 0.f;
  #pragma unroll
  for (int it = 0; it < 16; ++it) {
    const float* p = posPart + (it * 256 + t) * 12;
    fv4 a = *(const fv4*)p;
    fv4 b4 = *(const fv4*)(p + 4);
    float c8 = p[8];
    s[0]+=a.x; s[1]+=a.y; s[2]+=a.z; s[3]+=a.w;
    s[4]+=b4.x; s[5]+=b4.y; s[6]+=b4.z; s[7]+=b4.w;
    s[8]+=c8;
  }
  #pragma unroll
  for (int off = 32; off > 0; off >>= 1)
    #pragma unroll
    for (int i = 0; i < 9; ++i) s[i] += __shfl_xor(s[i], off, 64);
  if (lane == 0)
    #pragma unroll
    for (int i = 0; i < 9; ++i) red[w][i] = s[i];
  __syncthreads();
  if (t < 9) st[t] = red[0][t] + red[1][t] + red[2][t] + red[3][t];
  __syncthreads();
  if (t < 64) {
    int d = t;
    const float invN = 1.f / (float)NSAMP;
    float m0 = st[0]*invN, m1 = st[1]*invN, m2 = st[2]*invN;
    float C00 = st[3]*invN - m0*m0, C01 = st[4]*invN - m0*m1, C02 = st[5]*invN - m0*m2;
    float C11 = st[6]*invN - m1*m1, C12 = st[7]*invN - m1*m2, C22 = st[8]*invN - m2*m2;
    float w0 = Wp1[d*3], w1 = Wp1[d*3+1], w2 = Wp1[d*3+2];
    float mean = w0*m0 + w1*m1 + w2*m2 + bp1[d];
    float var = w0*w0*C00 + w1*w1*C11 + w2*w2*C22 + 2.f*(w0*w1*C01 + w0*w2*C02 + w1*w2*C12);
    float scale = gp[d] * rsqrtf(var + 1e-5f);
    Wp1f[d*3]   = scale * w0;
    Wp1f[d*3+1] = scale * w1;
    Wp1f[d*3+2] = scale * w2;
    bp1f[d] = btp[d] + scale * (bp1[d] - mean);
  }
}

// ---------------------------------------------------------------------------
// y-stats: Gram via MFMA. Grid 512 (16 pts/block)
// ---------------------------------------------------------------------------
__global__ __launch_bounds__(256) void k_ystats(
    const float* __restrict__ pq, const float* __restrict__ ps,
    const float* __restrict__ qT, const float* __restrict__ kT,
    const int* __restrict__ idxb,
    const float* __restrict__ Wp1f, const float* __restrict__ bp1f,
    const u16* __restrict__ Wp2bf, const float* __restrict__ bp2,
    float* __restrict__ Gpart, float* __restrict__ ySumPart) {
  __shared__ __align__(16) unsigned char smem[21760];
  u16*   hp   = (u16*)smem;                 // [64 s][72 i] bf16
  u16*   y2   = (u16*)(smem + 9216);        // [64 d][72 s] bf16
  float* r3   = (float*)(smem + 18432);     // 192
  float* qc   = (float*)(smem + 19200);     // 256
  int*   idxA = (int*)(smem + 20224);       // 64
  float* sWp1 = (float*)(smem + 20480);     // 192
  float* sbp1 = (float*)(smem + 21248);     // 64
  float* sbp2 = (float*)(smem + 21504);     // 64

  const int t = threadIdx.x;
  const int w = t >> 6, l = t & 63, lq = l >> 4, ln = l & 15;
  const int d0 = 16*w + lq*4;

  if (t < 192) sWp1[t] = Wp1f[t];
  if (t < 64){ sbp1[t] = bp1f[t]; sbp2[t] = bp2[t]; }

  bfv8 Ape[2];
  #pragma unroll
  for (int kk = 0; kk < 2; ++kk)
    Ape[kk] = *(const bfv8*)(Wp2bf + (16*w + ln)*64 + kk*32 + lq*8);

  fv4 gacc[4];
  #pragma unroll
  for (int nt = 0; nt < 4; ++nt) gacc[nt] = (fv4){0.f,0.f,0.f,0.f};
  float ys[4] = {0.f, 0.f, 0.f, 0.f};
  __syncthreads();

  for (int ch = 0; ch < 4; ++ch) {
    const int p0 = blockIdx.x * 16 + ch * 4;
    const int b  = p0 >> 11;
    const int bN = b * 2048;
    if (t < 64) idxA[t] = idxb[p0*16 + t];
    qc[t] = qT[(p0 + (t>>6))*64 + (t & 63)];
    __syncthreads();
    if (t < 192) { int c = t >> 6, s = t & 63; int n = (p0 + (s>>4)) & 2047;
      r3[c*64 + s] = pq[(b*3+c)*NN + n] - ps[(b*3+c)*MM + idxA[s]]; }
    __syncthreads();
    { int s = t >> 2, iq = t & 3;
      float r0 = r3[s], r1 = r3[64+s], r2 = r3[128+s];
      u16 tmp[16];
      #pragma unroll
      for (int e = 0; e < 16; ++e) { int i = iq*16 + e;
        float v = sbp1[i] + sWp1[i*3]*r0 + sWp1[i*3+1]*r1 + sWp1[i*3+2]*r2;
        tmp[e] = f2bf(fmaxf(v, 0.f)); }
      *(bfv8*)&hp[s*72 + iq*16]     = *(const bfv8*)&tmp[0];
      *(bfv8*)&hp[s*72 + iq*16 + 8] = *(const bfv8*)&tmp[8];
    }
    __syncthreads();
    {
      fv4 pe[4];
      #pragma unroll
      for (int nt = 0; nt < 4; ++nt) {
        fv4 acc = {0.f,0.f,0.f,0.f};
        #pragma unroll
        for (int kk = 0; kk < 2; ++kk) {
          bfv8 bb = *(const bfv8*)&hp[(nt*16 + ln)*72 + kk*32 + lq*8];
          acc = MFMA16(Ape[kk], bb, acc, 0, 0, 0);
        }
        pe[nt] = acc;
      }
      fv4 bp2q = *(const fv4*)&sbp2[d0];
      #pragma unroll
      for (int nt = 0; nt < 4; ++nt) {
        int s = nt*16 + ln;
        int mi = idxA[s];
        fv4 kg = *(const fv4*)(kT + (bN + mi)*64 + d0);
        fv4 qv = *(const fv4*)&qc[nt*64 + d0];
        fv4 yv = qv - kg + pe[nt] + bp2q;
        #pragma unroll
        for (int r = 0; r < 4; ++r) { y2[(d0 + r)*72 + s] = f2bf(yv[r]); ys[r] += yv[r]; }
      }
    }
    __syncthreads();
    #pragma unroll
    for (int kk = 0; kk < 2; ++kk) {
      bfv8 aa = *(const bfv8*)&y2[(16*w + ln)*72 + kk*32 + lq*8];
      #pragma unroll
      for (int nt = 0; nt < 4; ++nt) {
        bfv8 bb = *(const bfv8*)&y2[(nt*16 + ln)*72 + kk*32 + lq*8];
        gacc[nt] = MFMA16(aa, bb, gacc[nt], 0, 0, 0);
      }
    }
    __syncthreads();
  }
  #pragma unroll
  for (int nt = 0; nt < 4; ++nt)
    #pragma unroll
    for (int r = 0; r < 4; ++r)
      Gpart[blockIdx.x*4096 + (16*w + lq*4 + r)*64 + nt*16 + ln] = gacc[nt][r];
  #pragma unroll
  for (int off = 1; off <= 8; off <<= 1) {
    #pragma unroll
    for (int r = 0; r < 4; ++r) ys[r] += __shfl_xor(ys[r], off, 64);
  }
  if (ln == 0) {
    #pragma unroll
    for (int r = 0; r < 4; ++r) ySumPart[blockIdx.x*64 + d0 + r] = ys[r];
  }
}

// ---------------------------------------------------------------------------
// reduce Gram / ySum partials (512 blocks)
// ---------------------------------------------------------------------------
__global__ __launch_bounds__(256) void k_gred(
    const float* __restrict__ Gpart, const float* __restrict__ ySumPart,
    float* __restrict__ G, float* __restrict__ ySum) {
  int bid = blockIdx.x, t = threadIdx.x;   // grid 17
  if (bid < 16) {
    int j = bid*256 + t;
    float s = 0.f;
    for (int p = 0; p < 512; ++p) s += Gpart[p*4096 + j];
    G[j] = s;
  } else if (t < 64) {
    float s = 0.f;
    for (int p = 0; p < 512; ++p) s += ySumPart[p*64 + t];
    ySum[t] = s;
  }
}

// ---------------------------------------------------------------------------
// fold attn-BN into Wa1/ba1; emit bf16 Wa1f
// ---------------------------------------------------------------------------
__global__ __launch_bounds__(256) void k_attnfinal(
    const float* __restrict__ Wa1, const float* __restrict__ ba1,
    const float* __restrict__ ga, const float* __restrict__ bta,
    const float* __restrict__ ySum, const float* __restrict__ G,
    u16* __restrict__ Wa1fbf, float* __restrict__ ba1f) {
  __shared__ float red[256];
  __shared__ float mu[64];
  __shared__ float sc[1];
  int h = blockIdx.x, t = threadIdx.x;
  const float invN = 1.f / (float)NSAMP;
  if (t < 64) mu[t] = ySum[t] * invN;
  __syncthreads();
  float acc = 0.f;
  #pragma unroll
  for (int e = 0; e < 16; ++e) {
    int pi = t*16 + e, i = pi >> 6, j = pi & 63;
    float cov = G[pi]*invN - mu[i]*mu[j];
    acc += Wa1[h*64 + i] * Wa1[h*64 + j] * cov;
  }
  red[t] = acc;
  __syncthreads();
  for (int s = 128; s > 0; s >>= 1) { if (t < s) red[t] += red[t + s]; __syncthreads(); }
  float var = red[0];
  __syncthreads();
  red[t] = (t < 64) ? Wa1[h*64 + t] * mu[t] : 0.f;
  __syncthreads();
  for (int s = 128; s > 0; s >>= 1) { if (t < s) red[t] += red[t + s]; __syncthreads(); }
  if (t == 0) {
    float mean  = red[0] + ba1[h];
    float scale = ga[h] * rsqrtf(var + 1e-5f);
    sc[0] = scale;
    ba1f[h] = bta[h] + scale * (ba1[h] - mean);
  }
  __syncthreads();
  if (t < 64) Wa1fbf[h*64 + t] = f2bf(sc[0] * Wa1[h*64 + t]);
}

// ---------------------------------------------------------------------------
// main fused kernel (recompute) + fused epilogue. grid 512, 16 pts/block.
// ---------------------------------------------------------------------------
__global__ __launch_bounds__(256) void k_main(
    const float* __restrict__ pq, const float* __restrict__ ps,
    const float* __restrict__ qT, const float* __restrict__ kT, const float* __restrict__ vT,
    const int* __restrict__ idxb,
    const float* __restrict__ Wp1f, const float* __restrict__ bp1f,
    const u16* __restrict__ Wp2bf, const float* __restrict__ bp2,
    const u16* __restrict__ Wa1fbf, const float* __restrict__ ba1f,
    const u16* __restrict__ Wa2bf, const float* __restrict__ ba2,
    const u16* __restrict__ Webf, const float* __restrict__ be,
    const float* __restrict__ fq,
    u16* __restrict__ aggbf, float* __restrict__ out) {
  __shared__ __align__(16) unsigned char smem[65024];
  u16*   hp   = (u16*)smem;                    // [64 s][72 i] bf16 (aliases ha)
  u16*   ha   = (u16*)smem;                    // [64 s][264 h] bf16
  u16*   ylds = (u16*)(smem + 33792);          // [64 s][72 d] bf16 (aliases at)
  float* at   = (float*)(smem + 33792);        // [64 s][68 d] f32
  u16*   vt   = (u16*)(smem + 51200);          // [64 s][72 d] bf16
  float* r3   = (float*)(smem + 60416);        // 192
  float* qc   = (float*)(smem + 61184);        // 256
  int*   idxA = (int*)(smem + 62208);          // 64
  float* sWp1 = (float*)(smem + 62464);        // 192
  float* sbp1 = (float*)(smem + 63232);        // 64
  float* sbp2 = (float*)(smem + 63488);        // 64
  float* sba1 = (float*)(smem + 63744);        // 256
  float* sba2 = (float*)(smem + 64768);        // 64

  const int t = threadIdx.x;
  const int w = t >> 6, l = t & 63, lq = l >> 4, ln = l & 15;
  const int d0 = 16*w + lq*4;

  if (t < 192) sWp1[t] = Wp1f[t];
  if (t < 64){ sbp1[t] = bp1f[t]; sbp2[t] = bp2[t]; sba2[t] = ba2[t]; }
  sba1[t] = ba1f[t];

  bfv8 Ape[2], A1[4][2], A2[8];
  #pragma unroll
  for (int kk = 0; kk < 2; ++kk)
    Ape[kk] = *(const bfv8*)(Wp2bf + (16*w + ln)*64 + kk*32 + lq*8);
  #pragma unroll
  for (int mt = 0; mt < 4; ++mt)
    #pragma unroll
    for (int kk = 0; kk < 2; ++kk)
      A1[mt][kk] = *(const bfv8*)(Wa1fbf + (64*w + mt*16 + ln)*64 + kk*32 + lq*8);
  #pragma unroll
  for (int kk = 0; kk < 8; ++kk)
    A2[kk] = *(const bfv8*)(Wa2bf + (16*w + ln)*256 + kk*32 + lq*8);
  __syncthreads();

  for (int ch = 0; ch < 4; ++ch) {
    const int p0 = blockIdx.x * 16 + ch * 4;
    const int b  = p0 >> 11;
    const int bN = b * 2048;
    if (t < 64) idxA[t] = idxb[p0*16 + t];
    qc[t] = qT[(p0 + (t>>6))*64 + (t & 63)];
    __syncthreads();
    if (t < 192) { int c = t >> 6, s = t & 63; int n = (p0 + (s>>4)) & 2047;
      r3[c*64 + s] = pq[(b*3+c)*NN + n] - ps[(b*3+c)*MM + idxA[s]]; }
    __syncthreads();
    { int s = t >> 2, iq = t & 3;
      float r0 = r3[s], r1 = r3[64+s], r2 = r3[128+s];
      u16 tmp[16];
      #pragma unroll
      for (int e = 0; e < 16; ++e) { int i = iq*16 + e;
        float v = sbp1[i] + sWp1[i*3]*r0 + sWp1[i*3+1]*r1 + sWp1[i*3+2]*r2;
        tmp[e] = f2bf(fmaxf(v, 0.f)); }
      *(bfv8*)&hp[s*72 + iq*16]     = *(const bfv8*)&tmp[0];
      *(bfv8*)&hp[s*72 + iq*16 + 8] = *(const bfv8*)&tmp[8];
    }
    __syncthreads();
    {
      fv4 pe[4];
      #pragma unroll
      for (int nt = 0; nt < 4; ++nt) {
        fv4 acc = {0.f,0.f,0.f,0.f};
        #pragma unroll
        for (int kk = 0; kk < 2; ++kk) {
          bfv8 bb = *(const bfv8*)&hp[(nt*16 + ln)*72 + kk*32 + lq*8];
          acc = MFMA16(Ape[kk], bb, acc, 0, 0, 0);
        }
        pe[nt] = acc;
      }
      fv4 bp2q = *(const fv4*)&sbp2[d0];
      #pragma unroll
      for (int nt = 0; nt < 4; ++nt) {
        int s = nt*16 + ln;
        int mi = idxA[s];
        fv4 kg = *(const fv4*)(kT + (bN + mi)*64 + d0);
        fv4 vg = *(const fv4*)(vT + (bN + mi)*64 + d0);
        fv4 qv = *(const fv4*)&qc[nt*64 + d0];
        fv4 pv = pe[nt] + bp2q;
        fv4 yv = qv - kg + pv;
        fv4 vv = vg + pv;
        u16 yp[4], vp[4];
        #pragma unroll
        for (int r = 0; r < 4; ++r) { yp[r] = f2bf(yv[r]); vp[r] = f2bf(vv[r]); }
        *(bfv4*)&ylds[s*72 + d0] = *(const bfv4*)yp;
        *(bfv4*)&vt[s*72 + d0]   = *(const bfv4*)vp;
      }
    }
    __syncthreads();
    #pragma unroll
    for (int nt = 0; nt < 4; ++nt) {
      int s = nt*16 + ln;
      bfv8 b0 = *(const bfv8*)&ylds[s*72 + lq*8];
      bfv8 b1 = *(const bfv8*)&ylds[s*72 + 32 + lq*8];
      #pragma unroll
      for (int mt = 0; mt < 4; ++mt) {
        fv4 acc = {0.f,0.f,0.f,0.f};
        acc = MFMA16(A1[mt][0], b0, acc, 0, 0, 0);
        acc = MFMA16(A1[mt][1], b1, acc, 0, 0, 0);
        int h0 = 64*w + mt*16 + lq*4;
        fv4 bq = *(const fv4*)&sba1[h0];
        u16 hv[4];
        #pragma unroll
        for (int r = 0; r < 4; ++r) hv[r] = f2bf(fmaxf(acc[r] + bq[r], 0.f));
        *(bfv4*)&ha[s*264 + h0] = *(const bfv4*)hv;
      }
    }
    __syncthreads();
    {
      fv4 acc2[4];
      #pragma unroll
      for (int nt = 0; nt < 4; ++nt) acc2[nt] = (fv4){0.f,0.f,0.f,0.f};
      #pragma unroll
      for (int kk = 0; kk < 8; ++kk) {
        #pragma unroll
        for (int nt = 0; nt < 4; ++nt) {
          bfv8 bb = *(const bfv8*)&ha[(nt*16 + ln)*264 + kk*32 + lq*8];
          acc2[nt] = MFMA16(A2[kk], bb, acc2[nt], 0, 0, 0);
        }
      }
      fv4 ba2q = *(const fv4*)&sba2[d0];
      #pragma unroll
      for (int nt = 0; nt < 4; ++nt) {
        int s = nt*16 + ln;
        fv4 o = acc2[nt] + ba2q;
        *(fv4*)&at[s*68 + d0] = o;
      }
    }
    __syncthreads();
    {
      int dd = t & 63, pt = t >> 6;
      float a[16];
      #pragma unroll
      for (int k = 0; k < 16; ++k) a[k] = at[(pt*16 + k)*68 + dd];
      float mx = a[0];
      #pragma unroll
      for (int k = 1; k < 16; ++k) mx = fmaxf(mx, a[k]);
      float sum = 0.f, num = 0.f;
      #pragma unroll
      for (int k = 0; k < 16; ++k) {
        float e = __expf(a[k] - mx);
        sum += e;
        num += e * bf2f(vt[(pt*16 + k)*72 + dd]);
      }
      aggbf[(p0 + pt)*64 + dd] = f2bf(num / sum);
    }
    __syncthreads();
  }
  // ---- fused epilogue: out = We @ agg + be + fq for this block's 16 pts ----
  {
    const int P0 = blockIdx.x * 16;
    const int b  = P0 >> 11;
    const int n0 = P0 & 2047;
    bfv8 EA[2][2];
    #pragma unroll
    for (int mt = 0; mt < 2; ++mt)
      #pragma unroll
      for (int kk = 0; kk < 2; ++kk)
        EA[mt][kk] = *(const bfv8*)(Webf + ((w*2 + mt)*16 + ln)*64 + kk*32 + lq*8);
    const u16* bp = aggbf + (P0 + ln)*64;
    bfv8 b0 = *(const bfv8*)(bp + lq*8);
    bfv8 b1 = *(const bfv8*)(bp + 32 + lq*8);
    fv4 eacc[2];
    #pragma unroll
    for (int mt = 0; mt < 2; ++mt) {
      fv4 a = {0.f,0.f,0.f,0.f};
      a = MFMA16(EA[mt][0], b0, a, 0, 0, 0);
      a = MFMA16(EA[mt][1], b1, a, 0, 0, 0);
      eacc[mt] = a;
    }
    #pragma unroll
    for (int mt = 0; mt < 2; ++mt) {
      int c0 = (w*2 + mt)*16 + lq*4;
      fv4 bev = *(const fv4*)&be[c0];
      #pragma unroll
      for (int r = 0; r < 4; ++r) {
        int c = c0 + r;
        int o = (b*128 + c)*2048 + n0 + ln;
        out[o] = eacc[mt][r] + bev[r] + fq[o];
      }
    }
  }
}

// ---------------------------------------------------------------------------
extern "C" void kernel_launch(void* const* d_in, const int* in_sizes, int n_in,
                              void* d_out, int out_size, void* d_ws, size_t ws_size,
                              hipStream_t stream) {
  (void)in_sizes; (void)n_in; (void)out_size; (void)ws_size;
  const float* pq  = (const float*)d_in[0];
  const float* fq  = (const float*)d_in[1];
  const float* ps  = (const float*)d_in[2];
  const float* fs  = (const float*)d_in[3];
  const float* Wq  = (const float*)d_in[4];  const float* bq  = (const float*)d_in[5];
  const float* Wk  = (const float*)d_in[6];  const float* bk  = (const float*)d_in[7];
  const float* Wv  = (const float*)d_in[8];  const float* bv  = (const float*)d_in[9];
  const float* Wp1 = (const float*)d_in[10]; const float* bp1 = (const float*)d_in[11];
  const float* gp  = (const float*)d_in[12]; const float* btp = (const float*)d_in[13];
  const float* Wp2 = (const float*)d_in[14]; const float* bp2 = (const float*)d_in[15];
  const float* Wa1 = (const float*)d_in[16]; const float* ba1 = (const float*)d_in[17];
  const float* ga  = (const float*)d_in[18]; const float* bta = (const float*)d_in[19];
  const float* Wa2 = (const float*)d_in[20]; const float* ba2 = (const float*)d_in[21];
  const float* We  = (const float*)d_in[22]; const float* be  = (const float*)d_in[23];
  float* ws = (float*)d_ws;
  float* qT    = ws;                         // 524288
  float* kT    = ws + 524288;                // 524288
  float* vT    = ws + 1048576;               // 524288
  u16*   aggbf = (u16*)(ws + 1572864);       // 524288 fl region (1MB used)
  int*   idxb  = (int*)(ws + 2097152);       // 131072
  u16*   Wqbf  = (u16*)(ws + 2228224);       // 4096 fl each
  u16*   Wkbf  = (u16*)(ws + 2232320);
  u16*   Wvbf  = (u16*)(ws + 2236416);
  u16*   Webf  = (u16*)(ws + 2240512);
  fv4*   psP   = (fv4*)(ws + 2244608);       // 131072 fl
  float* Wp1f  = ws + 2375680;               // 192
  float* bp1f  = ws + 2375872;               // 64
  float* ba1f  = ws + 2375936;               // 256
  float* G     = ws + 2376192;               // 4096
  float* ySum  = ws + 2380288;               // 64
  float* ySumP = ws + 2380352;               // 32768 (512*64)
  u16*   Wp2bf  = (u16*)(ws + 2413120);      // 2048 fl
  u16*   Wa2bf  = (u16*)(ws + 2415168);      // 8192 fl
  u16*   Wa1fbf = (u16*)(ws + 2423360);      // 8192 fl
  float* posPart = ws + 2431552;             // 49152 (4096*12)
  float* Gpart   = ws + 2480704;             // 2097152 (512*4096)
  float* out   = (float*)d_out;

  k_prep<<<64, 256, 0, stream>>>(Wq, Wk, Wv, Wp2, Wa2, We, ps,
                                 Wqbf, Wkbf, Wvbf, Wp2bf, Wa2bf, Webf, psP);
  k_qkv<<<256, 256, 0, stream>>>(fq, fs, Wqbf, Wkbf, Wvbf, bq, bk, bv, qT, kT, vT);
  k_knn<<<4096, 128, 0, stream>>>(pq, psP, idxb, posPart);
  k_posfinal<<<1, 256, 0, stream>>>(Wp1, bp1, gp, btp, posPart, Wp1f, bp1f);
  k_ystats<<<512, 256, 0, stream>>>(pq, ps, qT, kT, idxb, Wp1f, bp1f, Wp2bf, bp2,
                                    Gpart, ySumP);
  k_gred<<<17, 256, 0, stream>>>(Gpart, ySumP, G, ySum);
  k_attnfinal<<<256, 256, 0, stream>>>(Wa1, ba1, ga, bta, ySum, G, Wa1fbf, ba1f);
  k_main<<<512, 256, 0, stream>>>(pq, ps, qT, kT, vT, idxb, Wp1f, bp1f, Wp2bf, bp2,
                                  Wa1fbf, ba1f, Wa2bf, ba2, Webf, be, fq, aggbf, out);
}

// Round 14
// 227.458 us; speedup vs baseline: 1.1815x; 1.0377x over previous
//
#include <hip/hip_runtime.h>
#include <stdint.h>

#define NN 2048
#define MM 2048
#define NSAMP 131072   // B*N*K

typedef float  fv4 __attribute__((ext_vector_type(4)));
typedef short  bfv8 __attribute__((ext_vector_type(8)));
typedef short  bfv4 __attribute__((ext_vector_type(4)));
typedef unsigned short u16;
typedef unsigned long long u64;

__device__ inline u16 f2bf(float x){
  unsigned u = __float_as_uint(x);
  return (u16)((u + 0x7FFFu + ((u>>16)&1u)) >> 16);
}
__device__ inline float bf2f(u16 u){ return __uint_as_float(((unsigned)u)<<16); }
#define MFMA16 __builtin_amdgcn_mfma_f32_16x16x32_bf16

// ---------------------------------------------------------------------------
// prep: bf16-pack all weights (k-contiguous row-major) + psP float4
// ---------------------------------------------------------------------------
__global__ __launch_bounds__(256) void k_prep(
    const float* __restrict__ Wq, const float* __restrict__ Wk, const float* __restrict__ Wv,
    const float* __restrict__ Wp2, const float* __restrict__ Wa2, const float* __restrict__ We,
    const float* __restrict__ ps,
    u16* __restrict__ Wqbf, u16* __restrict__ Wkbf, u16* __restrict__ Wvbf,
    u16* __restrict__ Wp2bf, u16* __restrict__ Wa2bf, u16* __restrict__ Webf,
    fv4* __restrict__ psP) {
  int gid = blockIdx.x * 256 + threadIdx.x;   // grid 64*256 = 16384
  if (gid < 8192)  { Wqbf[gid] = f2bf(Wq[gid]); Wkbf[gid] = f2bf(Wk[gid]);
                     Wvbf[gid] = f2bf(Wv[gid]); Webf[gid] = f2bf(We[gid]); }
  if (gid < 4096)  Wp2bf[gid] = f2bf(Wp2[gid]);     // (D,D) row-major
  if (gid < 16384) Wa2bf[gid] = f2bf(Wa2[gid]);     // (D,H) row-major
  if (gid < 8192)  { int b = gid >> 11, m = gid & 2047;
    float x = ps[(b*3+0)*MM + m], y = ps[(b*3+1)*MM + m], z = ps[(b*3+2)*MM + m];
    fv4 p; p.x = x; p.y = y; p.z = z; p.w = x*x + y*y + z*z;
    psP[gid] = p; }
}

// ---------------------------------------------------------------------------
// q/k/v via MFMA with FUSED transpose+pack of fq/fs
// ---------------------------------------------------------------------------
__global__ __launch_bounds__(256) void k_qkv(
    const float* __restrict__ fq, const float* __restrict__ fs,
    const u16* __restrict__ Wqbf, const u16* __restrict__ Wkbf, const u16* __restrict__ Wvbf,
    const float* __restrict__ bq, const float* __restrict__ bk, const float* __restrict__ bv,
    float* __restrict__ qT, float* __restrict__ kT, float* __restrict__ vT) {
  __shared__ u16 tile[2][32 * 136];
  int bid = blockIdx.x;            // 256
  int b = bid >> 6, p0 = (bid & 63) * 32;
  int t = threadIdx.x;
  int w = t >> 6, l = t & 63, lq = l >> 4, ln = l & 15;
  {
    int cq = t >> 3, n4 = (t & 7) * 4;
    #pragma unroll
    for (int it = 0; it < 4; ++it) {
      int c = it * 32 + cq;
      fv4 vq = *(const fv4*)&fq[(b*128 + c)*2048 + p0 + n4];
      fv4 vs = *(const fv4*)&fs[(b*128 + c)*2048 + p0 + n4];
      #pragma unroll
      for (int j = 0; j < 4; ++j) {
        tile[0][(n4 + j)*136 + c] = f2bf(vq[j]);
        tile[1][(n4 + j)*136 + c] = f2bf(vs[j]);
      }
    }
  }
  bfv8 A[3][4];
  #pragma unroll
  for (int mat = 0; mat < 3; ++mat) {
    const u16* W = mat == 0 ? Wqbf : (mat == 1 ? Wkbf : Wvbf);
    #pragma unroll
    for (int kk = 0; kk < 4; ++kk)
      A[mat][kk] = *(const bfv8*)(W + (w*16 + ln)*128 + kk*32 + lq*8);
  }
  __syncthreads();
  fv4 acc[3][2];
  #pragma unroll
  for (int mat = 0; mat < 3; ++mat) {
    const u16* tl = tile[mat == 0 ? 0 : 1];
    #pragma unroll
    for (int nt = 0; nt < 2; ++nt) {
      fv4 a = {0.f,0.f,0.f,0.f};
      #pragma unroll
      for (int kk = 0; kk < 4; ++kk) {
        bfv8 bb = *(const bfv8*)&tl[(nt*16 + ln)*136 + kk*32 + lq*8];
        a = MFMA16(A[mat][kk], bb, a, 0, 0, 0);
      }
      acc[mat][nt] = a;
    }
  }
  #pragma unroll
  for (int mat = 0; mat < 3; ++mat) {
    float* dst = mat == 0 ? qT : (mat == 1 ? kT : vT);
    const float* bia = mat == 0 ? bq : (mat == 1 ? bk : bv);
    fv4 bq4 = *(const fv4*)&bia[w*16 + lq*4];
    #pragma unroll
    for (int nt = 0; nt < 2; ++nt) {
      fv4 o = acc[mat][nt] + bq4;
      *(fv4*)&dst[(b*NN + p0 + nt*16 + ln)*64 + w*16 + lq*4] = o;
    }
  }
}

// ---------------------------------------------------------------------------
// KNN: per-lane bitonic top-16 of 32; extraction via FOUR 16-lane groups
// (register head-tracking, no cand LDS); final lane-bitonic sort of 64
// group-winners -> exact global top-16 asc. Fused pos-moment accumulation.
// ---------------------------------------------------------------------------
__global__ __launch_bounds__(128) void k_knn(
    const float* __restrict__ pq, const fv4* __restrict__ psP,
    int* __restrict__ idxb, float* __restrict__ posPart) {
  __shared__ u64 winLDS[2][64];
  __shared__ float sacc[2][9];
  int t = threadIdx.x, w = t >> 6, lane = t & 63;
  int qi = blockIdx.x * 2 + w;       // 0..8191
  int b = qi >> 11, n = qi & 2047;
  const float* pqb = pq + b * 3 * NN;
  const fv4* psb = psP + b * 2048;
  float qx = pqb[n], qy = pqb[NN + n], qz = pqb[2 * NN + n];
  float qq = qx * qx + qy * qy + qz * qz;

  u64 A[16], Bv[16];
  #pragma unroll
  for (int j = 0; j < 16; ++j) {
    int m = lane + 64 * j;
    fv4 P = psb[m];
    float d2 = qq + P.w - 2.f * (qx * P.x + qy * P.y + qz * P.z);
    unsigned bu = __float_as_uint(d2);
    bu = (bu & 0x80000000u) ? ~bu : (bu | 0x80000000u);
    A[j] = (((u64)bu) << 32) | (unsigned)m;
  }
  #pragma unroll
  for (int j = 0; j < 16; ++j) {
    int m = lane + 64 * (j + 16);
    fv4 P = psb[m];
    float d2 = qq + P.w - 2.f * (qx * P.x + qy * P.y + qz * P.z);
    unsigned bu = __float_as_uint(d2);
    bu = (bu & 0x80000000u) ? ~bu : (bu | 0x80000000u);
    Bv[j] = (((u64)bu) << 32) | (unsigned)m;
  }
  #pragma unroll
  for (int k = 2; k <= 16; k <<= 1) {
    #pragma unroll
    for (int j = k >> 1; j > 0; j >>= 1) {
      #pragma unroll
      for (int i = 0; i < 16; ++i) {
        int l2 = i ^ j;
        if (l2 > i) {
          bool up = ((i & k) == 0);
          { u64 x = A[i], y = A[l2];
            bool sw = up ? (y < x) : (x < y);
            A[i] = sw ? y : x;  A[l2] = sw ? x : y; }
          { u64 x = Bv[i], y = Bv[l2];
            bool sw = up ? (y < x) : (x < y);
            Bv[i] = sw ? y : x; Bv[l2] = sw ? x : y; }
        }
      }
    }
  }
  #pragma unroll
  for (int i = 0; i < 16; ++i) {
    u64 y = Bv[15 - i];
    A[i] = A[i] < y ? A[i] : y;
  }
  #pragma unroll
  for (int j = 8; j > 0; j >>= 1) {
    #pragma unroll
    for (int i = 0; i < 16; ++i) {
      int l2 = i ^ j;
      if (l2 > i) {
        u64 x = A[i], y = A[l2];
        bool sw = (y < x);
        A[i] = sw ? y : x;  A[l2] = sw ? x : y;
      }
    }
  }
  for (int r = 0; r < 16; ++r) {
    u64 v = A[0];
    u64 mv = v;
    #pragma unroll
    for (int off = 1; off <= 8; off <<= 1) {
      u64 o = __shfl_xor(mv, off, 64);
      mv = o < mv ? o : mv;
    }
    bool pop = (v == mv);
    #pragma unroll
    for (int i = 0; i < 15; ++i) A[i] = pop ? A[i+1] : A[i];
    A[15] = pop ? ~0ULL : A[15];
    if ((lane & 15) == 0) winLDS[w][(lane >> 4) * 16 + r] = mv;
  }
  u64 e = winLDS[w][lane];
  #pragma unroll
  for (int k = 2; k <= 64; k <<= 1) {
    #pragma unroll
    for (int j = k >> 1; j > 0; j >>= 1) {
      u64 x = __shfl_xor(e, j, 64);
      u64 lo = e < x ? e : x, hi = e < x ? x : e;
      bool up = ((lane & k) == 0);
      bool takeLo = (((lane & j) == 0) == up);
      e = takeLo ? lo : hi;
    }
  }
  if (lane < 16) idxb[qi * 16 + lane] = (int)(e & 0xFFFFFFFFu);
  winLDS[w][lane] = e;
  float s0=0.f,s1=0.f,s2=0.f,s3=0.f,s4=0.f,s5=0.f,s6=0.f,s7=0.f,s8=0.f;
  #pragma unroll 4
  for (int r = 0; r < 16; ++r) {
    unsigned m = (unsigned)(winLDS[w][r] & 0xFFFFFFFFu);
    fv4 P = psb[m];
    float r0 = qx - P.x, r1 = qy - P.y, r2 = qz - P.z;
    s0 += r0; s1 += r1; s2 += r2;
    s3 += r0*r0; s4 += r0*r1; s5 += r0*r2;
    s6 += r1*r1; s7 += r1*r2; s8 += r2*r2;
  }
  if (lane == 0) {
    sacc[w][0]=s0; sacc[w][1]=s1; sacc[w][2]=s2; sacc[w][3]=s3; sacc[w][4]=s4;
    sacc[w][5]=s5; sacc[w][6]=s6; sacc[w][7]=s7; sacc[w][8]=s8;
  }
  __syncthreads();
  if (t < 9) posPart[blockIdx.x * 12 + t] = sacc[0][t] + sacc[1][t];
}

// ---------------------------------------------------------------------------
// reduce pos partials (4096 records, PARALLEL) + fold pos-BN into Wp1/bp1
// ---------------------------------------------------------------------------
__global__ __launch_bounds__(256) void k_posfinal(
    const float* __restrict__ Wp1, const float* __restrict__ bp1,
    const float* __restrict__ gp, const float* __restrict__ btp,
    const float* __restrict__ posPart, float* __restrict__ Wp1f, float* __restrict__ bp1f) {
  __shared__ float red[4][9];
  __shared__ float st[9];
  int t = threadIdx.x;
  int w = t >> 6, lane = t & 63;
  float s[9];
  #pragma unroll
  for (int i = 0; i < 9; ++i) s[i] = 0.f;
  #pragma unroll
  for (int it = 0; it < 16; ++it) {
    const float* p = posPart + (it * 256 + t) * 12;
    fv4 a = *(const fv4*)p;
    fv4 b4 = *(const fv4*)(p + 4);
    float c8 = p[8];
    s[0]+=a.x; s[1]+=a.y; s[2]+=a.z; s[3]+=a.w;
    s[4]+=b4.x; s[5]+=b4.y; s[6]+=b4.z; s[7]+=b4.w;
    s[8]+=c8;
  }
  #pragma unroll
  for (int off = 32; off > 0; off >>= 1)
    #pragma unroll
    for (int i = 0; i < 9; ++i) s[i] += __shfl_xor(s[i], off, 64);
  if (lane == 0)
    #pragma unroll
    for (int i = 0; i < 9; ++i) red[w][i] = s[i];
  __syncthreads();
  if (t < 9) st[t] = red[0][t] + red[1][t] + red[2][t] + red[3][t];
  __syncthreads();
  if (t < 64) {
    int d = t;
    const float invN = 1.f / (float)NSAMP;
    float m0 = st[0]*invN, m1 = st[1]*invN, m2 = st[2]*invN;
    float C00 = st[3]*invN - m0*m0, C01 = st[4]*invN - m0*m1, C02 = st[5]*invN - m0*m2;
    float C11 = st[6]*invN - m1*m1, C12 = st[7]*invN - m1*m2, C22 = st[8]*invN - m2*m2;
    float w0 = Wp1[d*3], w1 = Wp1[d*3+1], w2 = Wp1[d*3+2];
    float mean = w0*m0 + w1*m1 + w2*m2 + bp1[d];
    float var = w0*w0*C00 + w1*w1*C11 + w2*w2*C22 + 2.f*(w0*w1*C01 + w0*w2*C02 + w1*w2*C12);
    float scale = gp[d] * rsqrtf(var + 1e-5f);
    Wp1f[d*3]   = scale * w0;
    Wp1f[d*3+1] = scale * w1;
    Wp1f[d*3+2] = scale * w2;
    bp1f[d] = btp[d] + scale * (bp1[d] - mean);
  }
}

// ---------------------------------------------------------------------------
// y-stats: Gram via MFMA. Grid 512 (16 pts/block)
// ---------------------------------------------------------------------------
__global__ __launch_bounds__(256) void k_ystats(
    const float* __restrict__ pq, const float* __restrict__ ps,
    const float* __restrict__ qT, const float* __restrict__ kT,
    const int* __restrict__ idxb,
    const float* __restrict__ Wp1f, const float* __restrict__ bp1f,
    const u16* __restrict__ Wp2bf, const float* __restrict__ bp2,
    float* __restrict__ Gpart, float* __restrict__ ySumPart) {
  __shared__ __align__(16) unsigned char smem[21760];
  u16*   hp   = (u16*)smem;                 // [64 s][72 i] bf16
  u16*   y2   = (u16*)(smem + 9216);        // [64 d][72 s] bf16
  float* r3   = (float*)(smem + 18432);     // 192
  float* qc   = (float*)(smem + 19200);     // 256
  int*   idxA = (int*)(smem + 20224);       // 64
  float* sWp1 = (float*)(smem + 20480);     // 192
  float* sbp1 = (float*)(smem + 21248);     // 64
  float* sbp2 = (float*)(smem + 21504);     // 64

  const int t = threadIdx.x;
  const int w = t >> 6, l = t & 63, lq = l >> 4, ln = l & 15;
  const int d0 = 16*w + lq*4;

  if (t < 192) sWp1[t] = Wp1f[t];
  if (t < 64){ sbp1[t] = bp1f[t]; sbp2[t] = bp2[t]; }

  bfv8 Ape[2];
  #pragma unroll
  for (int kk = 0; kk < 2; ++kk)
    Ape[kk] = *(const bfv8*)(Wp2bf + (16*w + ln)*64 + kk*32 + lq*8);

  fv4 gacc[4];
  #pragma unroll
  for (int nt = 0; nt < 4; ++nt) gacc[nt] = (fv4){0.f,0.f,0.f,0.f};
  float ys[4] = {0.f, 0.f, 0.f, 0.f};
  __syncthreads();

  for (int ch = 0; ch < 4; ++ch) {
    const int p0 = blockIdx.x * 16 + ch * 4;
    const int b  = p0 >> 11;
    const int bN = b * 2048;
    if (t < 64) idxA[t] = idxb[p0*16 + t];
    qc[t] = qT[(p0 + (t>>6))*64 + (t & 63)];
    __syncthreads();
    if (t < 192) { int c = t >> 6, s = t & 63; int n = (p0 + (s>>4)) & 2047;
      r3[c*64 + s] = pq[(b*3+c)*NN + n] - ps[(b*3+c)*MM + idxA[s]]; }
    __syncthreads();
    { int s = t >> 2, iq = t & 3;
      float r0 = r3[s], r1 = r3[64+s], r2 = r3[128+s];
      u16 tmp[16];
      #pragma unroll
      for (int e = 0; e < 16; ++e) { int i = iq*16 + e;
        float v = sbp1[i] + sWp1[i*3]*r0 + sWp1[i*3+1]*r1 + sWp1[i*3+2]*r2;
        tmp[e] = f2bf(fmaxf(v, 0.f)); }
      *(bfv8*)&hp[s*72 + iq*16]     = *(const bfv8*)&tmp[0];
      *(bfv8*)&hp[s*72 + iq*16 + 8] = *(const bfv8*)&tmp[8];
    }
    __syncthreads();
    {
      fv4 pe[4];
      #pragma unroll
      for (int nt = 0; nt < 4; ++nt) {
        fv4 acc = {0.f,0.f,0.f,0.f};
        #pragma unroll
        for (int kk = 0; kk < 2; ++kk) {
          bfv8 bb = *(const bfv8*)&hp[(nt*16 + ln)*72 + kk*32 + lq*8];
          acc = MFMA16(Ape[kk], bb, acc, 0, 0, 0);
        }
        pe[nt] = acc;
      }
      fv4 bp2q = *(const fv4*)&sbp2[d0];
      #pragma unroll
      for (int nt = 0; nt < 4; ++nt) {
        int s = nt*16 + ln;
        int mi = idxA[s];
        fv4 kg = *(const fv4*)(kT + (bN + mi)*64 + d0);
        fv4 qv = *(const fv4*)&qc[nt*64 + d0];
        fv4 yv = qv - kg + pe[nt] + bp2q;
        #pragma unroll
        for (int r = 0; r < 4; ++r) { y2[(d0 + r)*72 + s] = f2bf(yv[r]); ys[r] += yv[r]; }
      }
    }
    __syncthreads();
    #pragma unroll
    for (int kk = 0; kk < 2; ++kk) {
      bfv8 aa = *(const bfv8*)&y2[(16*w + ln)*72 + kk*32 + lq*8];
      #pragma unroll
      for (int nt = 0; nt < 4; ++nt) {
        bfv8 bb = *(const bfv8*)&y2[(nt*16 + ln)*72 + kk*32 + lq*8];
        gacc[nt] = MFMA16(aa, bb, gacc[nt], 0, 0, 0);
      }
    }
    __syncthreads();
  }
  #pragma unroll
  for (int nt = 0; nt < 4; ++nt)
    #pragma unroll
    for (int r = 0; r < 4; ++r)
      Gpart[blockIdx.x*4096 + (16*w + lq*4 + r)*64 + nt*16 + ln] = gacc[nt][r];
  #pragma unroll
  for (int off = 1; off <= 8; off <<= 1) {
    #pragma unroll
    for (int r = 0; r < 4; ++r) ys[r] += __shfl_xor(ys[r], off, 64);
  }
  if (ln == 0) {
    #pragma unroll
    for (int r = 0; r < 4; ++r) ySumPart[blockIdx.x*64 + d0 + r] = ys[r];
  }
}

// ---------------------------------------------------------------------------
// reduce Gram / ySum partials — PARALLEL. grid 65:
//  blocks 0..63: 64 G-columns each, 4 stripes x 128 partials
//  block  64   : ySum, 4 stripes x 128 partials
// ---------------------------------------------------------------------------
__global__ __launch_bounds__(256) void k_gred(
    const float* __restrict__ Gpart, const float* __restrict__ ySumPart,
    float* __restrict__ G, float* __restrict__ ySum) {
  __shared__ float red[256];
  int bid = blockIdx.x, t = threadIdx.x;
  int tj = t & 63, st = t >> 6;
  if (bid < 64) {
    int j = bid * 64 + tj;
    float s = 0.f;
    for (int p = st * 128; p < st * 128 + 128; ++p)
      s += Gpart[p*4096 + j];
    red[st * 64 + tj] = s;
    __syncthreads();
    if (t < 64)
      G[bid * 64 + t] = red[t] + red[64 + t] + red[128 + t] + red[192 + t];
  } else {
    float s = 0.f;
    for (int p = st * 128; p < st * 128 + 128; ++p)
      s += ySumPart[p*64 + tj];
    red[st * 64 + tj] = s;
    __syncthreads();
    if (t < 64)
      ySum[t] = red[t] + red[64 + t] + red[128 + t] + red[192 + t];
  }
}

// ---------------------------------------------------------------------------
// fold attn-BN into Wa1/ba1; emit bf16 Wa1f
// ---------------------------------------------------------------------------
__global__ __launch_bounds__(256) void k_attnfinal(
    const float* __restrict__ Wa1, const float* __restrict__ ba1,
    const float* __restrict__ ga, const float* __restrict__ bta,
    const float* __restrict__ ySum, const float* __restrict__ G,
    u16* __restrict__ Wa1fbf, float* __restrict__ ba1f) {
  __shared__ float red[256];
  __shared__ float mu[64];
  __shared__ float sc[1];
  int h = blockIdx.x, t = threadIdx.x;
  const float invN = 1.f / (float)NSAMP;
  if (t < 64) mu[t] = ySum[t] * invN;
  __syncthreads();
  float acc = 0.f;
  #pragma unroll
  for (int e = 0; e < 16; ++e) {
    int pi = t*16 + e, i = pi >> 6, j = pi & 63;
    float cov = G[pi]*invN - mu[i]*mu[j];
    acc += Wa1[h*64 + i] * Wa1[h*64 + j] * cov;
  }
  red[t] = acc;
  __syncthreads();
  for (int s = 128; s > 0; s >>= 1) { if (t < s) red[t] += red[t + s]; __syncthreads(); }
  float var = red[0];
  __syncthreads();
  red[t] = (t < 64) ? Wa1[h*64 + t] * mu[t] : 0.f;
  __syncthreads();
  for (int s = 128; s > 0; s >>= 1) { if (t < s) red[t] += red[t + s]; __syncthreads(); }
  if (t == 0) {
    float mean  = red[0] + ba1[h];
    float scale = ga[h] * rsqrtf(var + 1e-5f);
    sc[0] = scale;
    ba1f[h] = bta[h] + scale * (ba1[h] - mean);
  }
  __syncthreads();
  if (t < 64) Wa1fbf[h*64 + t] = f2bf(sc[0] * Wa1[h*64 + t]);
}

// ---------------------------------------------------------------------------
// main fused kernel (recompute) + fused epilogue. grid 512, 16 pts/block.
// ---------------------------------------------------------------------------
__global__ __launch_bounds__(256) void k_main(
    const float* __restrict__ pq, const float* __restrict__ ps,
    const float* __restrict__ qT, const float* __restrict__ kT, const float* __restrict__ vT,
    const int* __restrict__ idxb,
    const float* __restrict__ Wp1f, const float* __restrict__ bp1f,
    const u16* __restrict__ Wp2bf, const float* __restrict__ bp2,
    const u16* __restrict__ Wa1fbf, const float* __restrict__ ba1f,
    const u16* __restrict__ Wa2bf, const float* __restrict__ ba2,
    const u16* __restrict__ Webf, const float* __restrict__ be,
    const float* __restrict__ fq,
    u16* __restrict__ aggbf, float* __restrict__ out) {
  __shared__ __align__(16) unsigned char smem[65024];
  u16*   hp   = (u16*)smem;                    // [64 s][72 i] bf16 (aliases ha)
  u16*   ha   = (u16*)smem;                    // [64 s][264 h] bf16
  u16*   ylds = (u16*)(smem + 33792);          // [64 s][72 d] bf16 (aliases at)
  float* at   = (float*)(smem + 33792);        // [64 s][68 d] f32
  u16*   vt   = (u16*)(smem + 51200);          // [64 s][72 d] bf16
  float* r3   = (float*)(smem + 60416);        // 192
  float* qc   = (float*)(smem + 61184);        // 256
  int*   idxA = (int*)(smem + 62208);          // 64
  float* sWp1 = (float*)(smem + 62464);        // 192
  float* sbp1 = (float*)(smem + 63232);        // 64
  float* sbp2 = (float*)(smem + 63488);        // 64
  float* sba1 = (float*)(smem + 63744);        // 256
  float* sba2 = (float*)(smem + 64768);        // 64

  const int t = threadIdx.x;
  const int w = t >> 6, l = t & 63, lq = l >> 4, ln = l & 15;
  const int d0 = 16*w + lq*4;

  if (t < 192) sWp1[t] = Wp1f[t];
  if (t < 64){ sbp1[t] = bp1f[t]; sbp2[t] = bp2[t]; sba2[t] = ba2[t]; }
  sba1[t] = ba1f[t];

  bfv8 Ape[2], A1[4][2], A2[8];
  #pragma unroll
  for (int kk = 0; kk < 2; ++kk)
    Ape[kk] = *(const bfv8*)(Wp2bf + (16*w + ln)*64 + kk*32 + lq*8);
  #pragma unroll
  for (int mt = 0; mt < 4; ++mt)
    #pragma unroll
    for (int kk = 0; kk < 2; ++kk)
      A1[mt][kk] = *(const bfv8*)(Wa1fbf + (64*w + mt*16 + ln)*64 + kk*32 + lq*8);
  #pragma unroll
  for (int kk = 0; kk < 8; ++kk)
    A2[kk] = *(const bfv8*)(Wa2bf + (16*w + ln)*256 + kk*32 + lq*8);
  __syncthreads();

  for (int ch = 0; ch < 4; ++ch) {
    const int p0 = blockIdx.x * 16 + ch * 4;
    const int b  = p0 >> 11;
    const int bN = b * 2048;
    if (t < 64) idxA[t] = idxb[p0*16 + t];
    qc[t] = qT[(p0 + (t>>6))*64 + (t & 63)];
    __syncthreads();
    if (t < 192) { int c = t >> 6, s = t & 63; int n = (p0 + (s>>4)) & 2047;
      r3[c*64 + s] = pq[(b*3+c)*NN + n] - ps[(b*3+c)*MM + idxA[s]]; }
    __syncthreads();
    { int s = t >> 2, iq = t & 3;
      float r0 = r3[s], r1 = r3[64+s], r2 = r3[128+s];
      u16 tmp[16];
      #pragma unroll
      for (int e = 0; e < 16; ++e) { int i = iq*16 + e;
        float v = sbp1[i] + sWp1[i*3]*r0 + sWp1[i*3+1]*r1 + sWp1[i*3+2]*r2;
        tmp[e] = f2bf(fmaxf(v, 0.f)); }
      *(bfv8*)&hp[s*72 + iq*16]     = *(const bfv8*)&tmp[0];
      *(bfv8*)&hp[s*72 + iq*16 + 8] = *(const bfv8*)&tmp[8];
    }
    __syncthreads();
    {
      fv4 pe[4];
      #pragma unroll
      for (int nt = 0; nt < 4; ++nt) {
        fv4 acc = {0.f,0.f,0.f,0.f};
        #pragma unroll
        for (int kk = 0; kk < 2; ++kk) {
          bfv8 bb = *(const bfv8*)&hp[(nt*16 + ln)*72 + kk*32 + lq*8];
          acc = MFMA16(Ape[kk], bb, acc, 0, 0, 0);
        }
        pe[nt] = acc;
      }
      fv4 bp2q = *(const fv4*)&sbp2[d0];
      #pragma unroll
      for (int nt = 0; nt < 4; ++nt) {
        int s = nt*16 + ln;
        int mi = idxA[s];
        fv4 kg = *(const fv4*)(kT + (bN + mi)*64 + d0);
        fv4 vg = *(const fv4*)(vT + (bN + mi)*64 + d0);
        fv4 qv = *(const fv4*)&qc[nt*64 + d0];
        fv4 pv = pe[nt] + bp2q;
        fv4 yv = qv - kg + pv;
        fv4 vv = vg + pv;
        u16 yp[4], vp[4];
        #pragma unroll
        for (int r = 0; r < 4; ++r) { yp[r] = f2bf(yv[r]); vp[r] = f2bf(vv[r]); }
        *(bfv4*)&ylds[s*72 + d0] = *(const bfv4*)yp;
        *(bfv4*)&vt[s*72 + d0]   = *(const bfv4*)vp;
      }
    }
    __syncthreads();
    #pragma unroll
    for (int nt = 0; nt < 4; ++nt) {
      int s = nt*16 + ln;
      bfv8 b0 = *(const bfv8*)&ylds[s*72 + lq*8];
      bfv8 b1 = *(const bfv8*)&ylds[s*72 + 32 + lq*8];
      #pragma unroll
      for (int mt = 0; mt < 4; ++mt) {
        fv4 acc = {0.f,0.f,0.f,0.f};
        acc = MFMA16(A1[mt][0], b0, acc, 0, 0, 0);
        acc = MFMA16(A1[mt][1], b1, acc, 0, 0, 0);
        int h0 = 64*w + mt*16 + lq*4;
        fv4 bq = *(const fv4*)&sba1[h0];
        u16 hv[4];
        #pragma unroll
        for (int r = 0; r < 4; ++r) hv[r] = f2bf(fmaxf(acc[r] + bq[r], 0.f));
        *(bfv4*)&ha[s*264 + h0] = *(const bfv4*)hv;
      }
    }
    __syncthreads();
    {
      fv4 acc2[4];
      #pragma unroll
      for (int nt = 0; nt < 4; ++nt) acc2[nt] = (fv4){0.f,0.f,0.f,0.f};
      #pragma unroll
      for (int kk = 0; kk < 8; ++kk) {
        #pragma unroll
        for (int nt = 0; nt < 4; ++nt) {
          bfv8 bb = *(const bfv8*)&ha[(nt*16 + ln)*264 + kk*32 + lq*8];
          acc2[nt] = MFMA16(A2[kk], bb, acc2[nt], 0, 0, 0);
        }
      }
      fv4 ba2q = *(const fv4*)&sba2[d0];
      #pragma unroll
      for (int nt = 0; nt < 4; ++nt) {
        int s = nt*16 + ln;
        fv4 o = acc2[nt] + ba2q;
        *(fv4*)&at[s*68 + d0] = o;
      }
    }
    __syncthreads();
    {
      int dd = t & 63, pt = t >> 6;
      float a[16];
      #pragma unroll
      for (int k = 0; k < 16; ++k) a[k] = at[(pt*16 + k)*68 + dd];
      float mx = a[0];
      #pragma unroll
      for (int k = 1; k < 16; ++k) mx = fmaxf(mx, a[k]);
      float sum = 0.f, num = 0.f;
      #pragma unroll
      for (int k = 0; k < 16; ++k) {
        float e = __expf(a[k] - mx);
        sum += e;
        num += e * bf2f(vt[(pt*16 + k)*72 + dd]);
      }
      aggbf[(p0 + pt)*64 + dd] = f2bf(num / sum);
    }
    __syncthreads();
  }
  // ---- fused epilogue: out = We @ agg + be + fq for this block's 16 pts ----
  {
    const int P0 = blockIdx.x * 16;
    const int b  = P0 >> 11;
    const int n0 = P0 & 2047;
    bfv8 EA[2][2];
    #pragma unroll
    for (int mt = 0; mt < 2; ++mt)
      #pragma unroll
      for (int kk = 0; kk < 2; ++kk)
        EA[mt][kk] = *(const bfv8*)(Webf + ((w*2 + mt)*16 + ln)*64 + kk*32 + lq*8);
    const u16* bp = aggbf + (P0 + ln)*64;
    bfv8 b0 = *(const bfv8*)(bp + lq*8);
    bfv8 b1 = *(const bfv8*)(bp + 32 + lq*8);
    fv4 eacc[2];
    #pragma unroll
    for (int mt = 0; mt < 2; ++mt) {
      fv4 a = {0.f,0.f,0.f,0.f};
      a = MFMA16(EA[mt][0], b0, a, 0, 0, 0);
      a = MFMA16(EA[mt][1], b1, a, 0, 0, 0);
      eacc[mt] = a;
    }
    #pragma unroll
    for (int mt = 0; mt < 2; ++mt) {
      int c0 = (w*2 + mt)*16 + lq*4;
      fv4 bev = *(const fv4*)&be[c0];
      #pragma unroll
      for (int r = 0; r < 4; ++r) {
        int c = c0 + r;
        int o = (b*128 + c)*2048 + n0 + ln;
        out[o] = eacc[mt][r] + bev[r] + fq[o];
      }
    }
  }
}

// ---------------------------------------------------------------------------
extern "C" void kernel_launch(void* const* d_in, const int* in_sizes, int n_in,
                              void* d_out, int out_size, void* d_ws, size_t ws_size,
                              hipStream_t stream) {
  (void)in_sizes; (void)n_in; (void)out_size; (void)ws_size;
  const float* pq  = (const float*)d_in[0];
  const float* fq  = (const float*)d_in[1];
  const float* ps  = (const float*)d_in[2];
  const float* fs  = (const float*)d_in[3];
  const float* Wq  = (const float*)d_in[4];  const float* bq  = (const float*)d_in[5];
  const float* Wk  = (const float*)d_in[6];  const float* bk  = (const float*)d_in[7];
  const float* Wv  = (const float*)d_in[8];  const float* bv  = (const float*)d_in[9];
  const float* Wp1 = (const float*)d_in[10]; const float* bp1 = (const float*)d_in[11];
  const float* gp  = (const float*)d_in[12]; const float* btp = (const float*)d_in[13];
  const float* Wp2 = (const float*)d_in[14]; const float* bp2 = (const float*)d_in[15];
  const float* Wa1 = (const float*)d_in[16]; const float* ba1 = (const float*)d_in[17];
  const float* ga  = (const float*)d_in[18]; const float* bta = (const float*)d_in[19];
  const float* Wa2 = (const float*)d_in[20]; const float* ba2 = (const float*)d_in[21];
  const float* We  = (const float*)d_in[22]; const float* be  = (const float*)d_in[23];
  float* ws = (float*)d_ws;
  float* qT    = ws;                         // 524288
  float* kT    = ws + 524288;                // 524288
  float* vT    = ws + 1048576;               // 524288
  u16*   aggbf = (u16*)(ws + 1572864);       // 524288 fl region (1MB used)
  int*   idxb  = (int*)(ws + 2097152);       // 131072
  u16*   Wqbf  = (u16*)(ws + 2228224);       // 4096 fl each
  u16*   Wkbf  = (u16*)(ws + 2232320);
  u16*   Wvbf  = (u16*)(ws + 2236416);
  u16*   Webf  = (u16*)(ws + 2240512);
  fv4*   psP   = (fv4*)(ws + 2244608);       // 131072 fl
  float* Wp1f  = ws + 2375680;               // 192
  float* bp1f  = ws + 2375872;               // 64
  float* ba1f  = ws + 2375936;               // 256
  float* G     = ws + 2376192;               // 4096
  float* ySum  = ws + 2380288;               // 64
  float* ySumP = ws + 2380352;               // 32768 (512*64)
  u16*   Wp2bf  = (u16*)(ws + 2413120);      // 2048 fl
  u16*   Wa2bf  = (u16*)(ws + 2415168);      // 8192 fl
  u16*   Wa1fbf = (u16*)(ws + 2423360);      // 8192 fl
  float* posPart = ws + 2431552;             // 49152 (4096*12)
  float* Gpart   = ws + 2480704;             // 2097152 (512*4096)
  float* out   = (float*)d_out;

  k_prep<<<64, 256, 0, stream>>>(Wq, Wk, Wv, Wp2, Wa2, We, ps,
                                 Wqbf, Wkbf, Wvbf, Wp2bf, Wa2bf, Webf, psP);
  k_qkv<<<256, 256, 0, stream>>>(fq, fs, Wqbf, Wkbf, Wvbf, bq, bk, bv, qT, kT, vT);
  k_knn<<<4096, 128, 0, stream>>>(pq, psP, idxb, posPart);
  k_posfinal<<<1, 256, 0, stream>>>(Wp1, bp1, gp, btp, posPart, Wp1f, bp1f);
  k_ystats<<<512, 256, 0, stream>>>(pq, ps, qT, kT, idxb, Wp1f, bp1f, Wp2bf, bp2,
                                    Gpart, ySumP);
  k_gred<<<65, 256, 0, stream>>>(Gpart, ySumP, G, ySum);
  k_attnfinal<<<256, 256, 0, stream>>>(Wa1, ba1, ga, bta, ySum, G, Wa1fbf, ba1f);
  k_main<<<512, 256, 0, stream>>>(pq, ps, qT, kT, vT, idxb, Wp1f, bp1f, Wp2bf, bp2,
                                  Wa1fbf, ba1f, Wa2bf, ba2, Webf, be, fq, aggbf, out);
}